// Round 3
// baseline (2506.950 us; speedup 1.0000x reference)
//
#include <hip/hip_runtime.h>
#include <math.h>

#define BB 4096
#define TT 128
#define FF 256
#define HH 64
#define VV 32
#define LN_EPS 1e-3f

__device__ __forceinline__ float sigm(float x) { return 1.0f / (1.0f + expf(-x)); }

// ---------------- Kernel 1: LayerNorm + feature MLP -> seq [B,T,9] ----------------
__global__ __launch_bounds__(256, 2) void k_mlp(
    const float* __restrict__ X, const int* __restrict__ Yp,
    const float* __restrict__ lng, const float* __restrict__ lnb,
    const float* __restrict__ W1, const float* __restrict__ b1,
    const float* __restrict__ bng, const float* __restrict__ bnb,
    const float* __restrict__ bnm, const float* __restrict__ bnv,
    const float* __restrict__ W2, const float* __restrict__ b2,
    const float* __restrict__ W3, const float* __restrict__ b3,
    float* __restrict__ seq)
{
    __shared__ float w1s[FF * 32];
    __shared__ float w2s[32 * 16];
    __shared__ float w3s[16 * 8];
    __shared__ float lngs[FF], lnbs[FF];
    __shared__ float b1s[32], bnS[32], bnB[32], b2s[16], b3s[8];
    __shared__ __align__(16) float xns[4][FF];
    __shared__ float e1s[4][32], e2s[4][16];

    int tid = threadIdx.x;
    for (int i = tid; i < FF * 32; i += 256) w1s[i] = W1[i];
    for (int i = tid; i < 32 * 16; i += 256) w2s[i] = W2[i];
    for (int i = tid; i < 16 * 8;  i += 256) w3s[i] = W3[i];
    for (int i = tid; i < FF; i += 256) { lngs[i] = lng[i]; lnbs[i] = lnb[i]; }
    if (tid < 32) {
        b1s[tid] = b1[tid];
        float s = bng[tid] * rsqrtf(bnv[tid] + LN_EPS);
        bnS[tid] = s;
        bnB[tid] = bnb[tid] - bnm[tid] * s;
    } else if (tid < 48) b2s[tid - 32] = b2[tid - 32];
    else if (tid < 56) b3s[tid - 48] = b3[tid - 48];
    __syncthreads();

    int wv = tid >> 6, ln = tid & 63;
    const int total = BB * TT;
    // all 4 waves run the same trip count (524288 / 8192 = 64), so __syncthreads
    // inside the loop is safe (no divergence at barriers).
    for (int r = blockIdx.x * 4 + wv; r < total; r += gridDim.x * 4) {
        float4 x4 = *(const float4*)(X + (size_t)r * FF + ln * 4);
        float s  = x4.x + x4.y + x4.z + x4.w;
        float ss = x4.x * x4.x + x4.y * x4.y + x4.z * x4.z + x4.w * x4.w;
        #pragma unroll
        for (int m = 1; m < 64; m <<= 1) { s += __shfl_xor(s, m); ss += __shfl_xor(ss, m); }
        float mu = s * (1.0f / FF);
        float var = ss * (1.0f / FF) - mu * mu;
        float rs = rsqrtf(var + LN_EPS);
        float4 xn;
        xn.x = (x4.x - mu) * rs * lngs[ln * 4 + 0] + lnbs[ln * 4 + 0];
        xn.y = (x4.y - mu) * rs * lngs[ln * 4 + 1] + lnbs[ln * 4 + 1];
        xn.z = (x4.z - mu) * rs * lngs[ln * 4 + 2] + lnbs[ln * 4 + 2];
        xn.w = (x4.w - mu) * rs * lngs[ln * 4 + 3] + lnbs[ln * 4 + 3];
        *(float4*)&xns[wv][ln * 4] = xn;
        __syncthreads();

        // dense1: 256 -> 32. lane = (k, half); each half sums 128 inputs, combine via shfl.
        int k = ln & 31, hf = ln >> 5;
        const float* xp = &xns[wv][hf * 128];
        const float* wp = &w1s[hf * 128 * 32 + k];
        float acc = 0.f;
        #pragma unroll 8
        for (int j = 0; j < 128; ++j) acc += xp[j] * wp[j * 32];
        acc += __shfl_xor(acc, 32);
        float e1 = fmaxf(acc + b1s[k], 0.f);
        e1 = e1 * bnS[k] + bnB[k];
        if (ln < 32) e1s[wv][k] = e1;
        __syncthreads();

        if (ln < 16) {
            float a2 = b2s[ln];
            #pragma unroll
            for (int j = 0; j < 32; ++j) a2 += e1s[wv][j] * w2s[j * 16 + ln];
            e2s[wv][ln] = fmaxf(a2, 0.f);
        }
        __syncthreads();
        if (ln < 8) {
            float a3 = b3s[ln];
            #pragma unroll
            for (int j = 0; j < 16; ++j) a3 += e2s[wv][j] * w3s[j * 8 + ln];
            seq[(size_t)r * 9 + ln] = fmaxf(a3, 0.f);
        }
        if (ln == 8) seq[(size_t)r * 9 + 8] = (float)Yp[r];
        __syncthreads();
    }
}

// ------- Kernel 2: per-sample BiLSTM + attention + decoder + output softmax -------
__global__ __launch_bounds__(512, 2) void k_lstm(
    const float* __restrict__ seq,
    const float* __restrict__ fk, const float* __restrict__ fr, const float* __restrict__ fb,
    const float* __restrict__ bk, const float* __restrict__ br, const float* __restrict__ bb,
    const float* __restrict__ Wsh, const float* __restrict__ bsh,
    const float* __restrict__ Wsc, const float* __restrict__ bsc,
    const float* __restrict__ Wq,  const float* __restrict__ bq,
    const float* __restrict__ dk,  const float* __restrict__ dr, const float* __restrict__ db,
    const float* __restrict__ Wo,  const float* __restrict__ bo,
    float* __restrict__ out)
{
    __shared__ float seqs[TT * 9];
    __shared__ __align__(16) float hF[64];
    __shared__ __align__(16) float hB[64];
    __shared__ float cF[64], cB[64];
    __shared__ float zS[2][256];
    __shared__ float encs[TT][129];   // f32, odd row stride -> <=2-way bank aliasing (free)
    __shared__ float shS[64], scS[64], qS[128], pS[128], attS[128], zdS[256], hdS[64];
    __shared__ float red[8];

    int tid = threadIdx.x;
    int b = blockIdx.x;
    int wv = tid >> 6;        // 0..7
    int ln = tid & 63;
    int half = ln >> 5;       // 0 = fwd chain, 1 = bwd chain
    int lc = ln & 31;
    int col = wv * 32 + lc;   // gate column 0..255

    for (int i = tid; i < TT * 9; i += 512) seqs[i] = seq[(size_t)b * (TT * 9) + i];
    if (tid < 64) { hF[tid] = 0.f; hB[tid] = 0.f; cF[tid] = 0.f; cB[tid] = 0.f; }

    const float* Wk = half ? bk : fk;
    const float* Wr = half ? br : fr;
    const float* Bz = half ? bb : fb;
    float wk[9], wr[64];
    #pragma unroll
    for (int j = 0; j < 9; ++j) wk[j] = Wk[j * 256 + col];
    #pragma unroll
    for (int j = 0; j < 64; ++j) wr[j] = Wr[j * 256 + col];
    float bz = Bz[col];
    __syncthreads();

    const float* hsrc = half ? hB : hF;
    for (int t = 0; t < TT; ++t) {
        int ts = half ? (TT - 1 - t) : t;
        float z = bz;
        #pragma unroll
        for (int j = 0; j < 9; ++j) z += seqs[ts * 9 + j] * wk[j];
        #pragma unroll
        for (int j = 0; j < 64; j += 4) {
            float4 h4 = *(const float4*)(hsrc + j);
            z += h4.x * wr[j] + h4.y * wr[j + 1] + h4.z * wr[j + 2] + h4.w * wr[j + 3];
        }
        zS[half][col] = z;
        __syncthreads();
        if (wv < 2) {   // wv 0: fwd gates, wv 1: bwd gates; lane = hidden unit
            float zi = zS[wv][ln], zf = zS[wv][64 + ln], zg = zS[wv][128 + ln], zo = zS[wv][192 + ln];
            float* cp = wv ? cB : cF;
            float* hp = wv ? hB : hF;
            float c = sigm(zf) * cp[ln] + sigm(zi) * tanhf(zg);
            float h = sigm(zo) * tanhf(c);
            cp[ln] = c; hp[ln] = h;
            int tr = wv ? (TT - 1 - t) : t;
            encs[tr][wv * 64 + ln] = h;
        }
        __syncthreads();
    }

    // ---- state projections: sh = [hF,hB]@Wsh+bsh (tid<64), sc = [cF,cB]@Wsc+bsc (tid 64..127) ----
    if (tid < 128) {
        int u = tid & 63;
        const float* Wm = (tid < 64) ? Wsh : Wsc;
        float a = (tid < 64) ? bsh[u] : bsc[u];
        #pragma unroll 4
        for (int j = 0; j < 128; ++j) {
            float sv = (tid < 64) ? ((j < 64) ? hF[j] : hB[j - 64])    // hidden states -> sh
                                  : ((j < 64) ? cF[j] : cB[j - 64]);   // CELL  states -> sc
            a += sv * Wm[j * 64 + u];
        }
        if (tid < 64) shS[u] = a; else scS[u] = a;
    }
    __syncthreads();
    // ---- query ----
    if (tid < 128) {
        float a = bq[tid];
        #pragma unroll 4
        for (int u = 0; u < 64; ++u) a += shS[u] * Wq[u * 128 + tid];
        qS[tid] = a;
    }
    __syncthreads();
    // ---- attention scores + softmax-max ----
    float sc_val = 0.f;
    if (tid < 128) {
        float a = 0.f;
        #pragma unroll 4
        for (int d = 0; d < 128; ++d) a += qS[d] * encs[tid][d];
        sc_val = a;
        float m = a;
        #pragma unroll
        for (int mask = 1; mask < 64; mask <<= 1) m = fmaxf(m, __shfl_xor(m, mask));
        if (ln == 0) red[wv] = m;
    }
    __syncthreads();
    float gmax = fmaxf(red[0], red[1]);
    if (tid < 128) {
        float ev = expf(sc_val - gmax);
        pS[tid] = ev;
        float s2 = ev;
        #pragma unroll
        for (int mask = 1; mask < 64; mask <<= 1) s2 += __shfl_xor(s2, mask);
        if (ln == 0) red[4 + wv] = s2;
    }
    __syncthreads();
    float denom = red[4] + red[5];
    // ---- attention-weighted sum ----
    if (tid < 128) {
        float a = 0.f;
        #pragma unroll 4
        for (int t2 = 0; t2 < 128; ++t2) a += pS[t2] * encs[t2][tid];
        attS[tid] = a / denom;
    }
    __syncthreads();
    // ---- decoder pre-activations ----
    if (tid < 256) {
        float a = db[tid];
        #pragma unroll 4
        for (int j = 0; j < 128; ++j) a += attS[j] * dk[j * 256 + tid];
        #pragma unroll 4
        for (int j = 0; j < 64; ++j) a += shS[j] * dr[j * 256 + tid];
        zdS[tid] = a;
    }
    __syncthreads();
    // ---- decoder gates ----
    if (tid < 64) {
        float zi = zdS[tid], zf = zdS[64 + tid], zg = zdS[128 + tid], zo = zdS[192 + tid];
        float c = sigm(zf) * scS[tid] + sigm(zi) * tanhf(zg);
        hdS[tid] = sigm(zo) * tanhf(c);
    }
    __syncthreads();
    // ---- output logits + softmax over V=32 (one wave) ----
    if (tid < 32) {
        float a = bo[tid];
        #pragma unroll
        for (int u = 0; u < 64; ++u) a += hdS[u] * Wo[u * 32 + tid];
        float m = a;
        #pragma unroll
        for (int mask = 1; mask < 32; mask <<= 1) m = fmaxf(m, __shfl_xor(m, mask));
        float e = expf(a - m);
        float s2 = e;
        #pragma unroll
        for (int mask = 1; mask < 32; mask <<= 1) s2 += __shfl_xor(s2, mask);
        out[(size_t)b * VV + tid] = e / s2;
    }
}

extern "C" void kernel_launch(void* const* d_in, const int* in_sizes, int n_in,
                              void* d_out, int out_size, void* d_ws, size_t ws_size,
                              hipStream_t stream) {
    const float* X   = (const float*)d_in[0];
    const int*   Yp  = (const int*)d_in[1];
    const float* lng = (const float*)d_in[2];
    const float* lnb = (const float*)d_in[3];
    const float* W1  = (const float*)d_in[4];
    const float* b1  = (const float*)d_in[5];
    const float* bng = (const float*)d_in[6];
    const float* bnb = (const float*)d_in[7];
    const float* bnm = (const float*)d_in[8];
    const float* bnv = (const float*)d_in[9];
    const float* W2  = (const float*)d_in[10];
    const float* b2  = (const float*)d_in[11];
    const float* W3  = (const float*)d_in[12];
    const float* b3  = (const float*)d_in[13];
    const float* fk  = (const float*)d_in[14];
    const float* fr  = (const float*)d_in[15];
    const float* fb  = (const float*)d_in[16];
    const float* bk  = (const float*)d_in[17];
    const float* br  = (const float*)d_in[18];
    const float* bbv = (const float*)d_in[19];
    const float* Wsh = (const float*)d_in[20];
    const float* bsh = (const float*)d_in[21];
    const float* Wsc = (const float*)d_in[22];
    const float* bsc = (const float*)d_in[23];
    const float* Wq  = (const float*)d_in[24];
    const float* bq  = (const float*)d_in[25];
    const float* dk  = (const float*)d_in[26];
    const float* dr  = (const float*)d_in[27];
    const float* db  = (const float*)d_in[28];
    const float* Wo  = (const float*)d_in[29];
    const float* bo  = (const float*)d_in[30];

    float* seq = (float*)d_ws;   // [B,T,9] f32 = 18.9 MB

    k_mlp<<<2048, 256, 0, stream>>>(X, Yp, lng, lnb, W1, b1, bng, bnb, bnm, bnv,
                                    W2, b2, W3, b3, seq);
    k_lstm<<<BB, 512, 0, stream>>>(seq, fk, fr, fb, bk, br, bbv,
                                   Wsh, bsh, Wsc, bsc, Wq, bq, dk, dr, db, Wo, bo,
                                   (float*)d_out);
}

// Round 4
// 1182.008 us; speedup vs baseline: 2.1209x; 2.1209x over previous
//
#include <hip/hip_runtime.h>
#include <math.h>

#define BB 4096
#define TT 128
#define FF 256
#define VV 32
#define LN_EPS 1e-3f

typedef __attribute__((ext_vector_type(8))) short short8;
typedef __attribute__((ext_vector_type(4))) float f32x4;

__device__ __forceinline__ float sigm(float x) { return 1.0f / (1.0f + __expf(-x)); }
__device__ __forceinline__ float tanhfast(float x) { float e = __expf(2.0f * x); return 1.0f - 2.0f / (e + 1.0f); }
__device__ __forceinline__ unsigned short f2bf(float f) {
    union { float f; unsigned u; } v; v.f = f;
    unsigned r = v.u + 0x7FFFu + ((v.u >> 16) & 1u);   // RNE
    return (unsigned short)(r >> 16);
}
__device__ __forceinline__ float bf2f(unsigned short h) {
    union { unsigned u; float f; } v; v.u = ((unsigned)h) << 16; return v.f;
}

// ---------------- Kernel 1: LayerNorm + feature MLP -> seq [B,T,9] (unchanged, passing) ----
__global__ __launch_bounds__(256, 2) void k_mlp(
    const float* __restrict__ X, const int* __restrict__ Yp,
    const float* __restrict__ lng, const float* __restrict__ lnb,
    const float* __restrict__ W1, const float* __restrict__ b1,
    const float* __restrict__ bng, const float* __restrict__ bnb,
    const float* __restrict__ bnm, const float* __restrict__ bnv,
    const float* __restrict__ W2, const float* __restrict__ b2,
    const float* __restrict__ W3, const float* __restrict__ b3,
    float* __restrict__ seq)
{
    __shared__ float w1s[FF * 32];
    __shared__ float w2s[32 * 16];
    __shared__ float w3s[16 * 8];
    __shared__ float lngs[FF], lnbs[FF];
    __shared__ float b1s[32], bnS[32], bnB[32], b2s[16], b3s[8];
    __shared__ __align__(16) float xns[4][FF];
    __shared__ float e1s[4][32], e2s[4][16];

    int tid = threadIdx.x;
    for (int i = tid; i < FF * 32; i += 256) w1s[i] = W1[i];
    for (int i = tid; i < 32 * 16; i += 256) w2s[i] = W2[i];
    for (int i = tid; i < 16 * 8;  i += 256) w3s[i] = W3[i];
    for (int i = tid; i < FF; i += 256) { lngs[i] = lng[i]; lnbs[i] = lnb[i]; }
    if (tid < 32) {
        b1s[tid] = b1[tid];
        float s = bng[tid] * rsqrtf(bnv[tid] + LN_EPS);
        bnS[tid] = s;
        bnB[tid] = bnb[tid] - bnm[tid] * s;
    } else if (tid < 48) b2s[tid - 32] = b2[tid - 32];
    else if (tid < 56) b3s[tid - 48] = b3[tid - 48];
    __syncthreads();

    int wv = tid >> 6, ln = tid & 63;
    const int total = BB * TT;
    for (int r = blockIdx.x * 4 + wv; r < total; r += gridDim.x * 4) {
        float4 x4 = *(const float4*)(X + (size_t)r * FF + ln * 4);
        float s  = x4.x + x4.y + x4.z + x4.w;
        float ss = x4.x * x4.x + x4.y * x4.y + x4.z * x4.z + x4.w * x4.w;
        #pragma unroll
        for (int m = 1; m < 64; m <<= 1) { s += __shfl_xor(s, m); ss += __shfl_xor(ss, m); }
        float mu = s * (1.0f / FF);
        float var = ss * (1.0f / FF) - mu * mu;
        float rs = rsqrtf(var + LN_EPS);
        float4 xn;
        xn.x = (x4.x - mu) * rs * lngs[ln * 4 + 0] + lnbs[ln * 4 + 0];
        xn.y = (x4.y - mu) * rs * lngs[ln * 4 + 1] + lnbs[ln * 4 + 1];
        xn.z = (x4.z - mu) * rs * lngs[ln * 4 + 2] + lnbs[ln * 4 + 2];
        xn.w = (x4.w - mu) * rs * lngs[ln * 4 + 3] + lnbs[ln * 4 + 3];
        *(float4*)&xns[wv][ln * 4] = xn;
        __syncthreads();

        int k = ln & 31, hf = ln >> 5;
        const float* xp = &xns[wv][hf * 128];
        const float* wp = &w1s[hf * 128 * 32 + k];
        float acc = 0.f;
        #pragma unroll 8
        for (int j = 0; j < 128; ++j) acc += xp[j] * wp[j * 32];
        acc += __shfl_xor(acc, 32);
        float e1 = fmaxf(acc + b1s[k], 0.f);
        e1 = e1 * bnS[k] + bnB[k];
        if (ln < 32) e1s[wv][k] = e1;
        __syncthreads();

        if (ln < 16) {
            float a2 = b2s[ln];
            #pragma unroll
            for (int j = 0; j < 32; ++j) a2 += e1s[wv][j] * w2s[j * 16 + ln];
            e2s[wv][ln] = fmaxf(a2, 0.f);
        }
        __syncthreads();
        if (ln < 8) {
            float a3 = b3s[ln];
            #pragma unroll
            for (int j = 0; j < 16; ++j) a3 += e2s[wv][j] * w3s[j * 8 + ln];
            seq[(size_t)r * 9 + ln] = fmaxf(a3, 0.f);
        }
        if (ln == 8) seq[(size_t)r * 9 + 8] = (float)Yp[r];
        __syncthreads();
    }
}

// ------- Kernel 2: batched-16 MFMA BiLSTM. Block = 16 samples x 2 dirs (8 waves). -------
// z[16x256] = [h(64) | seq(9) | pad] (K=96, bf16 hi/lo split) @ Wext (split) + bias, 3-term MFMA.
// Wave w of dir d owns N-tiles {4g+w} -> lane holds all 4 gates of (4 samples, unit u) -> in-lane c/h.
__global__ __launch_bounds__(512, 2) void k_lstm2(
    const float* __restrict__ seq,
    const float* __restrict__ fk, const float* __restrict__ fr, const float* __restrict__ fb,
    const float* __restrict__ bk, const float* __restrict__ br, const float* __restrict__ bbv,
    unsigned short* __restrict__ enc,      // chunk-local [cs][T][128] bf16
    float* __restrict__ hfin, float* __restrict__ cfin,  // absolute [B][128]
    int s0)
{
    __shared__ unsigned short sqhi[TT][16][8];   // 32 KB  seq[0..7] hi
    __shared__ unsigned short sqlo[TT][16][8];   // 32 KB  seq[0..7] lo
    __shared__ float yv[TT][16];                 // 8 KB   seq[8] (Y, exact in bf16)
    __shared__ float hlds[2][2][16][68];         // 34 KB  [buf][dir][sample][unit pad68]

    const int tid = threadIdx.x;
    const int sbase = s0 + blockIdx.x * 16;

    for (int i = tid; i < 16 * TT * 9; i += 512) {
        int smp = i / (TT * 9);
        int rem = i - smp * (TT * 9);
        int t = rem / 9, j = rem - t * 9;
        float v = seq[(size_t)(sbase + smp) * (TT * 9) + rem];
        if (j < 8) {
            unsigned short hi = f2bf(v);
            sqhi[t][smp][j] = hi;
            sqlo[t][smp][j] = f2bf(v - bf2f(hi));
        } else yv[t][smp] = v;
    }
    for (int i = tid; i < 2 * 16 * 68; i += 512) (&hlds[0][0][0][0])[i] = 0.f;

    const int wv = tid >> 6, l = tid & 63;
    const int d = wv >> 2, w = wv & 3;
    const int r = l & 15, q = l >> 4;
    const int u = (w << 4) + r;                 // unit 0..63 owned in gate phase
    const float* Wr = d ? br : fr;
    const float* Wk = d ? bk : fk;
    const float* Bz = d ? bbv : fb;

    // B fragments (K=96 x N=16 per tile), hi/lo split, held in VGPRs.
    short8 Bh[3][4], Bl[3][4];
    float bz[4];
    #pragma unroll
    for (int g = 0; g < 4; ++g) {
        int col = (g << 6) + u;                 // global gate column (i,f,g,o blocks of 64)
        bz[g] = Bz[col];
        #pragma unroll
        for (int kt = 0; kt < 3; ++kt) {
            #pragma unroll
            for (int j = 0; j < 8; ++j) {
                int kg = kt * 32 + q * 8 + j;
                float v = (kg < 64) ? Wr[kg * 256 + col]
                        : (kg < 73) ? Wk[(kg - 64) * 256 + col] : 0.f;
                unsigned short hi = f2bf(v);
                Bh[kt][g][j] = (short)hi;
                Bl[kt][g][j] = (short)f2bf(v - bf2f(hi));
            }
        }
    }
    float c4[4] = {0.f, 0.f, 0.f, 0.f};
    __syncthreads();

    for (int t = 0; t < TT; ++t) {
        const int ts = d ? (TT - 1 - t) : t;
        const int buf = t & 1;

        // A fragments: row = l&15 (sample), k = q*8+j
        short8 A0h, A0l, A1h, A1l, A2h, A2l;
        {
            const float* hp = &hlds[buf][d][r][0];
            float4 a0 = *(const float4*)(hp + q * 8);
            float4 a1 = *(const float4*)(hp + q * 8 + 4);
            float4 a2 = *(const float4*)(hp + 32 + q * 8);
            float4 a3 = *(const float4*)(hp + 32 + q * 8 + 4);
            float hv[16] = {a0.x,a0.y,a0.z,a0.w, a1.x,a1.y,a1.z,a1.w,
                            a2.x,a2.y,a2.z,a2.w, a3.x,a3.y,a3.z,a3.w};
            #pragma unroll
            for (int j = 0; j < 8; ++j) {
                unsigned short h1 = f2bf(hv[j]);
                A0h[j] = (short)h1; A0l[j] = (short)f2bf(hv[j] - bf2f(h1));
                unsigned short h2 = f2bf(hv[8 + j]);
                A1h[j] = (short)h2; A1l[j] = (short)f2bf(hv[8 + j] - bf2f(h2));
            }
        }
        A2h = (short8){0,0,0,0,0,0,0,0};
        A2l = (short8){0,0,0,0,0,0,0,0};
        if (q == 0) {
            A2h = *(const short8*)&sqhi[ts][r][0];
            A2l = *(const short8*)&sqlo[ts][r][0];
        } else if (q == 1) {
            A2h[0] = (short)f2bf(yv[ts][r]);    // Y integer: exact, lo = 0
        }

        f32x4 zacc[4];
        #pragma unroll
        for (int g = 0; g < 4; ++g) {
            f32x4 acc = {bz[g], bz[g], bz[g], bz[g]};
            acc = __builtin_amdgcn_mfma_f32_16x16x32_bf16(A0h, Bh[0][g], acc, 0, 0, 0);
            acc = __builtin_amdgcn_mfma_f32_16x16x32_bf16(A0l, Bh[0][g], acc, 0, 0, 0);
            acc = __builtin_amdgcn_mfma_f32_16x16x32_bf16(A0h, Bl[0][g], acc, 0, 0, 0);
            acc = __builtin_amdgcn_mfma_f32_16x16x32_bf16(A1h, Bh[1][g], acc, 0, 0, 0);
            acc = __builtin_amdgcn_mfma_f32_16x16x32_bf16(A1l, Bh[1][g], acc, 0, 0, 0);
            acc = __builtin_amdgcn_mfma_f32_16x16x32_bf16(A1h, Bl[1][g], acc, 0, 0, 0);
            acc = __builtin_amdgcn_mfma_f32_16x16x32_bf16(A2h, Bh[2][g], acc, 0, 0, 0);
            acc = __builtin_amdgcn_mfma_f32_16x16x32_bf16(A2l, Bh[2][g], acc, 0, 0, 0);
            acc = __builtin_amdgcn_mfma_f32_16x16x32_bf16(A2h, Bl[2][g], acc, 0, 0, 0);
            zacc[g] = acc;
        }

        // gates: C/D row = q*4+i (sample), col = l&15 -> unit u of wave w
        #pragma unroll
        for (int i = 0; i < 4; ++i) {
            float zi = zacc[0][i], zf = zacc[1][i], zg = zacc[2][i], zo = zacc[3][i];
            float cc = sigm(zf) * c4[i] + sigm(zi) * tanhfast(zg);
            float hh = sigm(zo) * tanhfast(cc);
            c4[i] = cc;
            int smp = (q << 2) + i;
            hlds[buf ^ 1][d][smp][u] = hh;
            enc[(size_t)(blockIdx.x * 16 + smp) * (TT * 128) + ts * 128 + (d << 6) + u] = f2bf(hh);
            if (t == TT - 1) {
                hfin[(size_t)(sbase + smp) * 128 + (d << 6) + u] = hh;
                cfin[(size_t)(sbase + smp) * 128 + (d << 6) + u] = cc;
            }
        }
        __syncthreads();
    }
}

// ------- Kernel 3: per-sample attention + decoder + output softmax -------
__global__ __launch_bounds__(256, 4) void k_att(
    const unsigned short* __restrict__ enc,
    const float* __restrict__ hfin, const float* __restrict__ cfin,
    const float* __restrict__ Wsh, const float* __restrict__ bsh,
    const float* __restrict__ Wsc, const float* __restrict__ bsc,
    const float* __restrict__ Wq,  const float* __restrict__ bq,
    const float* __restrict__ dk,  const float* __restrict__ dr, const float* __restrict__ dbv,
    const float* __restrict__ Wo,  const float* __restrict__ bo,
    float* __restrict__ out, int s0)
{
    __shared__ unsigned short el[TT][136];   // bf16 enc tile, 16B-aligned rows
    __shared__ float st[128], ct[128], shS[64], scS[64], qS[128], pS[128], attS[128], zdS[256], hdS[64], red[8];

    int tid = threadIdx.x;
    int bloc = blockIdx.x;
    int s = s0 + bloc;

    for (int i = tid; i < TT * 16; i += 256) {
        int t = i >> 4, c = i & 15;
        *(short8*)&el[t][c * 8] = *(const short8*)&enc[(size_t)bloc * TT * 128 + t * 128 + c * 8];
    }
    if (tid < 128) { st[tid] = hfin[(size_t)s * 128 + tid]; ct[tid] = cfin[(size_t)s * 128 + tid]; }
    __syncthreads();

    if (tid < 128) {
        int uu = tid & 63;
        const float* Wm = (tid < 64) ? Wsh : Wsc;
        const float* sv = (tid < 64) ? st : ct;
        float a = (tid < 64) ? bsh[uu] : bsc[uu];
        #pragma unroll 4
        for (int j = 0; j < 128; ++j) a += sv[j] * Wm[j * 64 + uu];
        if (tid < 64) shS[uu] = a; else scS[uu] = a;
    }
    __syncthreads();
    if (tid < 128) {
        float a = bq[tid];
        #pragma unroll 4
        for (int uu = 0; uu < 64; ++uu) a += shS[uu] * Wq[uu * 128 + tid];
        qS[tid] = a;
    }
    __syncthreads();
    float sc_val = 0.f;
    int wvv = tid >> 6, lnn = tid & 63;
    if (tid < 128) {
        float a = 0.f;
        #pragma unroll 2
        for (int c = 0; c < 16; ++c) {
            short8 e8 = *(const short8*)&el[tid][c * 8];
            #pragma unroll
            for (int j2 = 0; j2 < 8; ++j2) a += qS[c * 8 + j2] * bf2f((unsigned short)e8[j2]);
        }
        sc_val = a;
        float m = a;
        #pragma unroll
        for (int mk = 1; mk < 64; mk <<= 1) m = fmaxf(m, __shfl_xor(m, mk));
        if (lnn == 0) red[wvv] = m;
    }
    __syncthreads();
    float gmax = fmaxf(red[0], red[1]);
    if (tid < 128) {
        float ev = expf(sc_val - gmax);
        pS[tid] = ev;
        float s2 = ev;
        #pragma unroll
        for (int mk = 1; mk < 64; mk <<= 1) s2 += __shfl_xor(s2, mk);
        if (lnn == 0) red[4 + wvv] = s2;
    }
    __syncthreads();
    float denom = red[4] + red[5];
    if (tid < 128) {
        float a = 0.f;
        #pragma unroll 4
        for (int t2 = 0; t2 < TT; ++t2) a += pS[t2] * bf2f(el[t2][tid]);
        attS[tid] = a / denom;
    }
    __syncthreads();
    if (tid < 256) {
        float a = dbv[tid];
        #pragma unroll 4
        for (int j = 0; j < 128; ++j) a += attS[j] * dk[j * 256 + tid];
        #pragma unroll 4
        for (int j = 0; j < 64; ++j)  a += shS[j] * dr[j * 256 + tid];
        zdS[tid] = a;
    }
    __syncthreads();
    if (tid < 64) {
        float zi = zdS[tid], zf = zdS[64 + tid], zg = zdS[128 + tid], zo = zdS[192 + tid];
        float cc = sigm(zf) * scS[tid] + sigm(zi) * tanhfast(zg);
        hdS[tid] = sigm(zo) * tanhfast(cc);
    }
    __syncthreads();
    if (tid < 32) {
        float a = bo[tid];
        #pragma unroll
        for (int uu = 0; uu < 64; ++uu) a += hdS[uu] * Wo[uu * 32 + tid];
        float m = a;
        #pragma unroll
        for (int mk = 1; mk < 32; mk <<= 1) m = fmaxf(m, __shfl_xor(m, mk));
        float e = expf(a - m);
        float s2 = e;
        #pragma unroll
        for (int mk = 1; mk < 32; mk <<= 1) s2 += __shfl_xor(s2, mk);
        out[(size_t)s * VV + tid] = e / s2;
    }
}

extern "C" void kernel_launch(void* const* d_in, const int* in_sizes, int n_in,
                              void* d_out, int out_size, void* d_ws, size_t ws_size,
                              hipStream_t stream) {
    const float* X   = (const float*)d_in[0];
    const int*   Yp  = (const int*)d_in[1];
    const float* lng = (const float*)d_in[2];
    const float* lnb = (const float*)d_in[3];
    const float* W1  = (const float*)d_in[4];
    const float* b1  = (const float*)d_in[5];
    const float* bng = (const float*)d_in[6];
    const float* bnb = (const float*)d_in[7];
    const float* bnm = (const float*)d_in[8];
    const float* bnv = (const float*)d_in[9];
    const float* W2  = (const float*)d_in[10];
    const float* b2  = (const float*)d_in[11];
    const float* W3  = (const float*)d_in[12];
    const float* b3  = (const float*)d_in[13];
    const float* fk  = (const float*)d_in[14];
    const float* fr  = (const float*)d_in[15];
    const float* fb  = (const float*)d_in[16];
    const float* bk  = (const float*)d_in[17];
    const float* br  = (const float*)d_in[18];
    const float* bbv = (const float*)d_in[19];
    const float* Wsh = (const float*)d_in[20];
    const float* bsh = (const float*)d_in[21];
    const float* Wsc = (const float*)d_in[22];
    const float* bsc = (const float*)d_in[23];
    const float* Wq  = (const float*)d_in[24];
    const float* bq  = (const float*)d_in[25];
    const float* dk  = (const float*)d_in[26];
    const float* dr  = (const float*)d_in[27];
    const float* db  = (const float*)d_in[28];
    const float* Wo  = (const float*)d_in[29];
    const float* bo  = (const float*)d_in[30];

    // ws layout: seq f32 [B,T,9] | hfin f32 [B,128] | cfin f32 [B,128] | enc bf16
    const size_t seqN  = (size_t)BB * TT * 9;
    const size_t finN  = (size_t)BB * 128;
    float* seqp  = (float*)d_ws;
    float* hfinp = seqp + seqN;
    float* cfinp = hfinp + finN;
    unsigned short* encp = (unsigned short*)(cfinp + finN);
    const size_t base_bytes = (seqN + 2 * finN) * sizeof(float);
    const size_t enc_full   = (size_t)BB * TT * 128 * sizeof(unsigned short);

    int nch = (ws_size >= base_bytes + enc_full) ? 1 : 8;   // chunked fallback if ws is small
    const int cs = BB / nch;

    k_mlp<<<2048, 256, 0, stream>>>(X, Yp, lng, lnb, W1, b1, bng, bnb, bnm, bnv,
                                    W2, b2, W3, b3, seqp);
    for (int c = 0; c < nch; ++c) {
        int ss0 = c * cs;
        k_lstm2<<<cs / 16, 512, 0, stream>>>(seqp, fk, fr, fb, bk, br, bbv,
                                             encp, hfinp, cfinp, ss0);
        k_att<<<cs, 256, 0, stream>>>(encp, hfinp, cfinp, Wsh, bsh, Wsc, bsc, Wq, bq,
                                      dk, dr, db, Wo, bo, (float*)d_out, ss0);
    }
}

// Round 5
// 1159.892 us; speedup vs baseline: 2.1614x; 1.0191x over previous
//
#include <hip/hip_runtime.h>
#include <math.h>

#define BB 4096
#define TT 128
#define FF 256
#define VV 32
#define LN_EPS 1e-3f

typedef __attribute__((ext_vector_type(8))) short short8;
typedef __attribute__((ext_vector_type(4))) float f32x4;

__device__ __forceinline__ float sigm(float x) { return 1.0f / (1.0f + __expf(-x)); }
__device__ __forceinline__ float tanhfast(float x) { float e = __expf(2.0f * x); return 1.0f - 2.0f / (e + 1.0f); }
__device__ __forceinline__ unsigned short f2bf(float f) {
    union { float f; unsigned u; } v; v.f = f;
    unsigned r = v.u + 0x7FFFu + ((v.u >> 16) & 1u);   // RNE
    return (unsigned short)(r >> 16);
}
__device__ __forceinline__ float bf2f(unsigned short h) {
    union { unsigned u; float f; } v; v.u = ((unsigned)h) << 16; return v.f;
}

// =================== Kernel 1: LN + MLP via MFMA -> packed seq ===================
// One wave per 16 rows. A-frag: row=l&15, k=(l>>4)*8+j. gamma folded into W1,
// beta folded into bias. hi/lo bf16 split keeps f32 accuracy. No block barriers
// in the main loop (wave-private LDS scratch).
__global__ __launch_bounds__(256, 3) void k_mlp2(
    const float* __restrict__ X, const int* __restrict__ Yp,
    const float* __restrict__ lng, const float* __restrict__ lnb,
    const float* __restrict__ W1, const float* __restrict__ b1,
    const float* __restrict__ bng, const float* __restrict__ bnb,
    const float* __restrict__ bnm, const float* __restrict__ bnv,
    const float* __restrict__ W2, const float* __restrict__ b2,
    const float* __restrict__ W3, const float* __restrict__ b3,
    unsigned int* __restrict__ sqpk, unsigned short* __restrict__ yv)
{
    __shared__ unsigned short w1fh[8192], w1fl[8192];   // [ks][nt][lane][j]
    __shared__ unsigned short w2fh[512], w2fl[512];     // [lane][j]
    __shared__ unsigned short w3fh[512], w3fl[512];
    __shared__ float bD1[32], bnSs[32], bnBs[32], b2s[16], b3s[8];
    __shared__ float e1s[4][16][33];
    __shared__ float e2s[4][16][17];

    const int tid = threadIdx.x;
    for (int e = tid; e < 8192; e += 256) {
        int j = e & 7, lane = (e >> 3) & 63, nt = (e >> 9) & 1, ks = e >> 10;
        int c = ks * 32 + (lane >> 4) * 8 + j;
        int n = nt * 16 + (lane & 15);
        float v = lng[c] * W1[c * 32 + n];
        unsigned short hi = f2bf(v);
        w1fh[e] = hi; w1fl[e] = f2bf(v - bf2f(hi));
    }
    for (int e = tid; e < 512; e += 256) {
        int j = e & 7, lane = e >> 3;
        int k = (lane >> 4) * 8 + j, n = lane & 15;
        float v2 = W2[k * 16 + n];
        unsigned short h2 = f2bf(v2);
        w2fh[e] = h2; w2fl[e] = f2bf(v2 - bf2f(h2));
        float v3 = (k < 16 && n < 8) ? W3[k * 8 + n] : 0.f;
        unsigned short h3 = f2bf(v3);
        w3fh[e] = h3; w3fl[e] = f2bf(v3 - bf2f(h3));
    }
    if (tid < 32) {
        float a = b1[tid];
        for (int c2 = 0; c2 < 256; ++c2) a += lnb[c2] * W1[c2 * 32 + tid];
        bD1[tid] = a;
        float sc = bng[tid] * rsqrtf(bnv[tid] + LN_EPS);
        bnSs[tid] = sc; bnBs[tid] = bnb[tid] - bnm[tid] * sc;
    } else if (tid < 48) b2s[tid - 32] = b2[tid - 32];
    else if (tid < 56) b3s[tid - 48] = b3[tid - 48];
    __syncthreads();

    const int wv = tid >> 6, l = tid & 63;
    const int r = l & 15, q = l >> 4;
    const int ntiles = (BB * TT) / 16;   // 32768
    for (int tile = blockIdx.x * 4 + wv; tile < ntiles; tile += gridDim.x * 4) {
        const size_t rowbase = (size_t)tile * 16;
        const float* xrow = X + (rowbase + r) * FF + q * 8;
        float xd[64];
        #pragma unroll
        for (int ks = 0; ks < 8; ++ks) {
            float4 p0 = *(const float4*)(xrow + ks * 32);
            float4 p1 = *(const float4*)(xrow + ks * 32 + 4);
            xd[ks * 8 + 0] = p0.x; xd[ks * 8 + 1] = p0.y; xd[ks * 8 + 2] = p0.z; xd[ks * 8 + 3] = p0.w;
            xd[ks * 8 + 4] = p1.x; xd[ks * 8 + 5] = p1.y; xd[ks * 8 + 6] = p1.z; xd[ks * 8 + 7] = p1.w;
        }
        float s = 0.f, ss = 0.f;
        #pragma unroll
        for (int i = 0; i < 64; ++i) { s += xd[i]; ss += xd[i] * xd[i]; }
        s += __shfl_xor(s, 16);  s += __shfl_xor(s, 32);
        ss += __shfl_xor(ss, 16); ss += __shfl_xor(ss, 32);
        float mu = s * (1.0f / FF);
        float var = ss * (1.0f / FF) - mu * mu;
        float rs = rsqrtf(var + LN_EPS);

        // dense1 (256->32) : 2 n-tiles, 8 k-steps, hi/lo
        f32x4 acc0 = {bD1[r], bD1[r], bD1[r], bD1[r]};
        f32x4 acc1 = {bD1[16 + r], bD1[16 + r], bD1[16 + r], bD1[16 + r]};
        #pragma unroll
        for (int ks = 0; ks < 8; ++ks) {
            short8 ah, al;
            #pragma unroll
            for (int j = 0; j < 8; ++j) {
                float xn = (xd[ks * 8 + j] - mu) * rs;
                unsigned short hi = f2bf(xn);
                ah[j] = (short)hi; al[j] = (short)f2bf(xn - bf2f(hi));
            }
            short8 bh0 = *(const short8*)&w1fh[((ks * 2 + 0) * 64 + l) * 8];
            short8 bl0 = *(const short8*)&w1fl[((ks * 2 + 0) * 64 + l) * 8];
            short8 bh1 = *(const short8*)&w1fh[((ks * 2 + 1) * 64 + l) * 8];
            short8 bl1 = *(const short8*)&w1fl[((ks * 2 + 1) * 64 + l) * 8];
            acc0 = __builtin_amdgcn_mfma_f32_16x16x32_bf16(ah, bh0, acc0, 0, 0, 0);
            acc0 = __builtin_amdgcn_mfma_f32_16x16x32_bf16(al, bh0, acc0, 0, 0, 0);
            acc0 = __builtin_amdgcn_mfma_f32_16x16x32_bf16(ah, bl0, acc0, 0, 0, 0);
            acc1 = __builtin_amdgcn_mfma_f32_16x16x32_bf16(ah, bh1, acc1, 0, 0, 0);
            acc1 = __builtin_amdgcn_mfma_f32_16x16x32_bf16(al, bh1, acc1, 0, 0, 0);
            acc1 = __builtin_amdgcn_mfma_f32_16x16x32_bf16(ah, bl1, acc1, 0, 0, 0);
        }
        // e1 = relu -> BN, write scratch (row=q*4+i, col=channel)
        #pragma unroll
        for (int i = 0; i < 4; ++i) {
            int row = q * 4 + i;
            float z0 = fmaxf(acc0[i], 0.f) * bnSs[r] + bnBs[r];
            float z1 = fmaxf(acc1[i], 0.f) * bnSs[16 + r] + bnBs[16 + r];
            e1s[wv][row][r] = z0;
            e1s[wv][row][16 + r] = z1;
        }
        __builtin_amdgcn_wave_barrier();

        // dense2 (32->16), K=32 exact
        short8 a2h, a2l;
        #pragma unroll
        for (int j = 0; j < 8; ++j) {
            float v = e1s[wv][r][q * 8 + j];
            unsigned short hi = f2bf(v);
            a2h[j] = (short)hi; a2l[j] = (short)f2bf(v - bf2f(hi));
        }
        f32x4 acc2 = {b2s[r], b2s[r], b2s[r], b2s[r]};
        {
            short8 bh = *(const short8*)&w2fh[l * 8];
            short8 bl = *(const short8*)&w2fl[l * 8];
            acc2 = __builtin_amdgcn_mfma_f32_16x16x32_bf16(a2h, bh, acc2, 0, 0, 0);
            acc2 = __builtin_amdgcn_mfma_f32_16x16x32_bf16(a2l, bh, acc2, 0, 0, 0);
            acc2 = __builtin_amdgcn_mfma_f32_16x16x32_bf16(a2h, bl, acc2, 0, 0, 0);
        }
        #pragma unroll
        for (int i = 0; i < 4; ++i) e2s[wv][q * 4 + i][r] = fmaxf(acc2[i], 0.f);
        __builtin_amdgcn_wave_barrier();

        // dense3 (16->8), K padded to 32 with zeros
        short8 a3h = (short8){0,0,0,0,0,0,0,0}, a3l = (short8){0,0,0,0,0,0,0,0};
        if (q < 2) {
            #pragma unroll
            for (int j = 0; j < 8; ++j) {
                float v = e2s[wv][r][q * 8 + j];
                unsigned short hi = f2bf(v);
                a3h[j] = (short)hi; a3l[j] = (short)f2bf(v - bf2f(hi));
            }
        }
        float b3v = (r < 8) ? b3s[r] : 0.f;
        f32x4 acc3 = {b3v, b3v, b3v, b3v};
        {
            short8 bh = *(const short8*)&w3fh[l * 8];
            short8 bl = *(const short8*)&w3fl[l * 8];
            acc3 = __builtin_amdgcn_mfma_f32_16x16x32_bf16(a3h, bh, acc3, 0, 0, 0);
            acc3 = __builtin_amdgcn_mfma_f32_16x16x32_bf16(a3l, bh, acc3, 0, 0, 0);
            acc3 = __builtin_amdgcn_mfma_f32_16x16x32_bf16(a3h, bl, acc3, 0, 0, 0);
        }
        // store packed hi/lo seq features + Y (bf16-exact int)
        if (r < 8) {
            #pragma unroll
            for (int i = 0; i < 4; ++i) {
                size_t grow = rowbase + q * 4 + i;
                float e3 = fmaxf(acc3[i], 0.f);
                unsigned short hi = f2bf(e3);
                unsigned short lo = f2bf(e3 - bf2f(hi));
                sqpk[grow * 8 + r] = ((unsigned)hi << 16) | (unsigned)lo;
            }
        } else if (r == 8) {
            #pragma unroll
            for (int i = 0; i < 4; ++i) {
                size_t grow = rowbase + q * 4 + i;
                yv[grow] = f2bf((float)Yp[grow]);
            }
        }
        __builtin_amdgcn_wave_barrier();
    }
}

// ====== Kernel 2: fused BiLSTM (3-pass) + exact attention + decoder + output ======
// Block = 16 samples, 8 waves (2 dirs x 4). No enc materialization:
//  P1 recurrence -> finals -> sh/sc/q.  P2 recurrence + per-t score halves (diag MFMA).
//  softmax (exact).  P3 recurrence + p-weighted att accumulation.  Head in-block.
#define A_SQPK 0u
#define A_YV   65536u
#define A_HLDS 69632u
#define A_SGRID 104448u   // also hfin/cfin (P1 end) and zd (head)
#define A_SH   120832u
#define A_SC   124928u
#define A_Q    129024u    // also pT[128][16] after P2
#define A_ATT  137216u    // also hd (head)
#define A_L    145408u
#define A_SZ   145472u

__global__ __launch_bounds__(512, 1) void k_rnn(
    const unsigned int* __restrict__ g_sqpk, const unsigned short* __restrict__ g_yv,
    const float* __restrict__ fk, const float* __restrict__ fr, const float* __restrict__ fb,
    const float* __restrict__ bk, const float* __restrict__ br, const float* __restrict__ bbv,
    const float* __restrict__ Wsh, const float* __restrict__ bsh,
    const float* __restrict__ Wsc, const float* __restrict__ bsc,
    const float* __restrict__ Wq,  const float* __restrict__ bq,
    const float* __restrict__ dk,  const float* __restrict__ dr, const float* __restrict__ db,
    const float* __restrict__ Wo,  const float* __restrict__ bo,
    float* __restrict__ out)
{
    __shared__ __align__(16) unsigned char arena[A_SZ];
    unsigned int*  sqpkS = (unsigned int*)(arena + A_SQPK);    // [128][16][8]
    unsigned short* yvS  = (unsigned short*)(arena + A_YV);    // [128][16]
    float* hldsF = (float*)(arena + A_HLDS);                   // [2][2][16][68]
    float* sgridF = (float*)(arena + A_SGRID);                 // [2][16][128]
    float* hfinL = (float*)(arena + A_SGRID);                  // [16][128]
    float* cfinL = hfinL + 2048;
    float* zdS   = (float*)(arena + A_SGRID);                  // [16][256] (head)
    float* shS   = (float*)(arena + A_SH);                     // [16][64]
    float* scS   = (float*)(arena + A_SC);
    float* qS    = (float*)(arena + A_Q);                      // [16][128]
    float* pT    = (float*)(arena + A_Q);                      // [128][16] (post-P2)
    float* attS  = (float*)(arena + A_ATT);                    // [16][128]
    float* hdS   = (float*)(arena + A_ATT);                    // [16][64] (head)
    float* lS    = (float*)(arena + A_L);                      // [16]

    const int tid = threadIdx.x;
    const int sbase = blockIdx.x * 16;
    const int wv = tid >> 6, l = tid & 63;
    const int d = wv >> 2, w = wv & 3;
    const int r = l & 15, q = l >> 4;
    const int u = (w << 4) + r;

    // stage packed seq
    for (int i = tid; i < 16 * TT * 8; i += 512) {
        int smp = i >> 10, rem = i & 1023;
        int t = rem >> 3, j = rem & 7;
        sqpkS[(t * 16 + smp) * 8 + j] = g_sqpk[(size_t)(sbase + smp) * (TT * 8) + rem];
    }
    for (int i = tid; i < 16 * TT; i += 512) {
        int smp = i >> 7, t = i & 127;
        yvS[t * 16 + smp] = g_yv[(size_t)(sbase + smp) * TT + t];
    }

    // recurrence B fragments (proven layout from round 4)
    const float* Wr = d ? br : fr;
    const float* Wk = d ? bk : fk;
    const float* Bz = d ? bbv : fb;
    short8 Bh[3][4], Bl[3][4];
    float bz[4];
    #pragma unroll
    for (int g = 0; g < 4; ++g) {
        int col = (g << 6) + u;
        bz[g] = Bz[col];
        #pragma unroll
        for (int kt = 0; kt < 3; ++kt) {
            #pragma unroll
            for (int j = 0; j < 8; ++j) {
                int kg = kt * 32 + q * 8 + j;
                float v = (kg < 64) ? Wr[kg * 256 + col]
                        : (kg < 73) ? Wk[(kg - 64) * 256 + col] : 0.f;
                unsigned short hi = f2bf(v);
                Bh[kt][g][j] = (short)hi;
                Bl[kt][g][j] = (short)f2bf(v - bf2f(hi));
            }
        }
    }
    short8 Bq0h = (short8){0,0,0,0,0,0,0,0}, Bq1h = (short8){0,0,0,0,0,0,0,0};
    __syncthreads();

    auto run_phase = [&](int mode) {
        for (int i = tid; i < 2 * 2 * 16 * 68; i += 512) hldsF[i] = 0.f;
        float c4[4] = {0.f, 0.f, 0.f, 0.f};
        float aacc[4] = {0.f, 0.f, 0.f, 0.f};
        __syncthreads();
        for (int t = 0; t < TT; ++t) {
            const int ts = d ? (TT - 1 - t) : t;
            const int buf = t & 1;
            short8 A0h, A0l, A1h, A1l, A2h, A2l;
            {
                const float* hp = hldsF + ((buf * 2 + d) * 16 + r) * 68;
                float4 a0 = *(const float4*)(hp + q * 8);
                float4 a1 = *(const float4*)(hp + q * 8 + 4);
                float4 a2 = *(const float4*)(hp + 32 + q * 8);
                float4 a3 = *(const float4*)(hp + 32 + q * 8 + 4);
                float hv[16] = {a0.x,a0.y,a0.z,a0.w, a1.x,a1.y,a1.z,a1.w,
                                a2.x,a2.y,a2.z,a2.w, a3.x,a3.y,a3.z,a3.w};
                #pragma unroll
                for (int j = 0; j < 8; ++j) {
                    unsigned short h1 = f2bf(hv[j]);
                    A0h[j] = (short)h1; A0l[j] = (short)f2bf(hv[j] - bf2f(h1));
                    unsigned short h2 = f2bf(hv[8 + j]);
                    A1h[j] = (short)h2; A1l[j] = (short)f2bf(hv[8 + j] - bf2f(h2));
                }
            }
            A2h = (short8){0,0,0,0,0,0,0,0};
            A2l = (short8){0,0,0,0,0,0,0,0};
            if (q == 0) {
                const unsigned int* sp = &sqpkS[(ts * 16 + r) * 8];
                uint4 w0 = *(const uint4*)sp;
                uint4 w1 = *(const uint4*)(sp + 4);
                A2h[0] = (short)(w0.x >> 16); A2l[0] = (short)(w0.x & 0xFFFF);
                A2h[1] = (short)(w0.y >> 16); A2l[1] = (short)(w0.y & 0xFFFF);
                A2h[2] = (short)(w0.z >> 16); A2l[2] = (short)(w0.z & 0xFFFF);
                A2h[3] = (short)(w0.w >> 16); A2l[3] = (short)(w0.w & 0xFFFF);
                A2h[4] = (short)(w1.x >> 16); A2l[4] = (short)(w1.x & 0xFFFF);
                A2h[5] = (short)(w1.y >> 16); A2l[5] = (short)(w1.y & 0xFFFF);
                A2h[6] = (short)(w1.z >> 16); A2l[6] = (short)(w1.z & 0xFFFF);
                A2h[7] = (short)(w1.w >> 16); A2l[7] = (short)(w1.w & 0xFFFF);
            } else if (q == 1) {
                A2h[0] = (short)yvS[ts * 16 + r];
            }
            if (mode == 1 && w == 0 && t > 0) {      // score of previous step's h
                f32x4 sa = {0.f, 0.f, 0.f, 0.f};
                sa = __builtin_amdgcn_mfma_f32_16x16x32_bf16(A0h, Bq0h, sa, 0, 0, 0);
                sa = __builtin_amdgcn_mfma_f32_16x16x32_bf16(A1h, Bq1h, sa, 0, 0, 0);
                if (q == (r >> 2)) {
                    int tp = d ? (TT - t) : (t - 1);
                    sgridF[(d * 16 + r) * 128 + tp] = sa[r & 3];
                }
            }
            f32x4 z[4];
            #pragma unroll
            for (int g = 0; g < 4; ++g) {
                f32x4 acc = {bz[g], bz[g], bz[g], bz[g]};
                acc = __builtin_amdgcn_mfma_f32_16x16x32_bf16(A0h, Bh[0][g], acc, 0, 0, 0);
                acc = __builtin_amdgcn_mfma_f32_16x16x32_bf16(A0l, Bh[0][g], acc, 0, 0, 0);
                acc = __builtin_amdgcn_mfma_f32_16x16x32_bf16(A0h, Bl[0][g], acc, 0, 0, 0);
                acc = __builtin_amdgcn_mfma_f32_16x16x32_bf16(A1h, Bh[1][g], acc, 0, 0, 0);
                acc = __builtin_amdgcn_mfma_f32_16x16x32_bf16(A1l, Bh[1][g], acc, 0, 0, 0);
                acc = __builtin_amdgcn_mfma_f32_16x16x32_bf16(A1h, Bl[1][g], acc, 0, 0, 0);
                acc = __builtin_amdgcn_mfma_f32_16x16x32_bf16(A2h, Bh[2][g], acc, 0, 0, 0);
                acc = __builtin_amdgcn_mfma_f32_16x16x32_bf16(A2l, Bh[2][g], acc, 0, 0, 0);
                acc = __builtin_amdgcn_mfma_f32_16x16x32_bf16(A2h, Bl[2][g], acc, 0, 0, 0);
                z[g] = acc;
            }
            #pragma unroll
            for (int i = 0; i < 4; ++i) {
                float zi = z[0][i], zf = z[1][i], zg = z[2][i], zo = z[3][i];
                float cc = sigm(zf) * c4[i] + sigm(zi) * tanhfast(zg);
                float hh = sigm(zo) * tanhfast(cc);
                c4[i] = cc;
                int smp = (q << 2) + i;
                hldsF[(((buf ^ 1) * 2 + d) * 16 + smp) * 68 + u] = hh;
                if (mode == 2) aacc[i] += pT[ts * 16 + smp] * hh;
                if (mode == 0 && t == TT - 1) {
                    hfinL[smp * 128 + (d << 6) + u] = hh;
                    cfinL[smp * 128 + (d << 6) + u] = cc;
                }
            }
            __syncthreads();
        }
        if (mode == 1) {   // epilogue: score of the final h (fwd t=127 / bwd t=0)
            if (w == 0) {
                const float* hp = hldsF + ((0 * 2 + d) * 16 + r) * 68;
                short8 A0h, A1h;
                #pragma unroll
                for (int j = 0; j < 8; ++j) {
                    A0h[j] = (short)f2bf(hp[q * 8 + j]);
                    A1h[j] = (short)f2bf(hp[32 + q * 8 + j]);
                }
                f32x4 sa = {0.f, 0.f, 0.f, 0.f};
                sa = __builtin_amdgcn_mfma_f32_16x16x32_bf16(A0h, Bq0h, sa, 0, 0, 0);
                sa = __builtin_amdgcn_mfma_f32_16x16x32_bf16(A1h, Bq1h, sa, 0, 0, 0);
                if (q == (r >> 2)) {
                    int tp = d ? 0 : (TT - 1);
                    sgridF[(d * 16 + r) * 128 + tp] = sa[r & 3];
                }
            }
            __syncthreads();
        }
        if (mode == 2) {
            #pragma unroll
            for (int i = 0; i < 4; ++i) {
                int smp = (q << 2) + i;
                attS[smp * 128 + (d << 6) + u] = aacc[i] / lS[smp];
            }
            __syncthreads();
        }
    };

    // ---- P1: recurrence -> finals ----
    run_phase(0);
    // sh (from hidden finals), sc (from CELL finals)
    for (int o = tid; o < 2048; o += 512) {
        int kind = o >> 10, smp = (o >> 6) & 15, uu = o & 63;
        const float* src = kind ? (cfinL + smp * 128) : (hfinL + smp * 128);
        const float* Wm = kind ? Wsc : Wsh;
        float a = kind ? bsc[uu] : bsh[uu];
        #pragma unroll 4
        for (int j = 0; j < 128; ++j) a += src[j] * Wm[j * 64 + uu];
        (kind ? scS : shS)[smp * 64 + uu] = a;
    }
    __syncthreads();
    for (int o = tid; o < 2048; o += 512) {
        int smp = o >> 7, dd = o & 127;
        float a = bq[dd];
        #pragma unroll 4
        for (int j = 0; j < 64; ++j) a += shS[smp * 64 + j] * Wq[j * 128 + dd];
        qS[smp * 128 + dd] = a;
    }
    __syncthreads();
    if (w == 0) {   // query B-fragments (col = sample, k = unit)
        #pragma unroll
        for (int j = 0; j < 8; ++j) {
            Bq0h[j] = (short)f2bf(qS[r * 128 + (d << 6) + 0 * 32 + q * 8 + j]);
            Bq1h[j] = (short)f2bf(qS[r * 128 + (d << 6) + 1 * 32 + q * 8 + j]);
        }
    }
    __syncthreads();

    // ---- P2: recurrence + score halves ----
    run_phase(1);
    // exact softmax over t (32 threads per sample)
    {
        int smp = tid >> 5, sl = tid & 31;
        float sv[4];
        #pragma unroll
        for (int p = 0; p < 4; ++p) {
            int t = sl + 32 * p;
            sv[p] = sgridF[smp * 128 + t] + sgridF[(16 + smp) * 128 + t];
        }
        float m = fmaxf(fmaxf(sv[0], sv[1]), fmaxf(sv[2], sv[3]));
        #pragma unroll
        for (int mk = 1; mk < 32; mk <<= 1) m = fmaxf(m, __shfl_xor(m, mk));
        float lsum = 0.f;
        #pragma unroll
        for (int p = 0; p < 4; ++p) lsum += __expf(sv[p] - m);
        #pragma unroll
        for (int mk = 1; mk < 32; mk <<= 1) lsum += __shfl_xor(lsum, mk);
        __syncthreads();              // sgrid reads done; pT overwrites qS region
        #pragma unroll
        for (int p = 0; p < 4; ++p) pT[(sl + 32 * p) * 16 + smp] = __expf(sv[p] - m);
        if (sl == 0) lS[smp] = lsum;
    }
    __syncthreads();

    // ---- P3: recurrence + weighted accumulation -> attS ----
    run_phase(2);

    // ---- head: decoder + output softmax ----
    for (int o = tid; o < 4096; o += 512) {
        int smp = o >> 8, col = o & 255;
        float a = db[col];
        #pragma unroll 4
        for (int j = 0; j < 128; ++j) a += attS[smp * 128 + j] * dk[j * 256 + col];
        #pragma unroll 4
        for (int j = 0; j < 64; ++j)  a += shS[smp * 64 + j] * dr[j * 256 + col];
        zdS[smp * 256 + col] = a;
    }
    __syncthreads();
    for (int o = tid; o < 1024; o += 512) {
        int smp = o >> 6, uu = o & 63;
        float zi = zdS[smp * 256 + uu], zf = zdS[smp * 256 + 64 + uu];
        float zg = zdS[smp * 256 + 128 + uu], zo = zdS[smp * 256 + 192 + uu];
        float cc = sigm(zf) * scS[smp * 64 + uu] + sigm(zi) * tanhfast(zg);
        hdS[smp * 64 + uu] = sigm(zo) * tanhfast(cc);
    }
    __syncthreads();
    {
        int smp = tid >> 5, v = tid & 31;
        float a = bo[v];
        #pragma unroll 4
        for (int j = 0; j < 64; ++j) a += hdS[smp * 64 + j] * Wo[j * 32 + v];
        float m = a;
        #pragma unroll
        for (int mk = 1; mk < 32; mk <<= 1) m = fmaxf(m, __shfl_xor(m, mk));
        float e = __expf(a - m);
        float s2 = e;
        #pragma unroll
        for (int mk = 1; mk < 32; mk <<= 1) s2 += __shfl_xor(s2, mk);
        out[(size_t)(sbase + smp) * VV + v] = e / s2;
    }
}

extern "C" void kernel_launch(void* const* d_in, const int* in_sizes, int n_in,
                              void* d_out, int out_size, void* d_ws, size_t ws_size,
                              hipStream_t stream) {
    const float* X   = (const float*)d_in[0];
    const int*   Yp  = (const int*)d_in[1];
    const float* lng = (const float*)d_in[2];
    const float* lnb = (const float*)d_in[3];
    const float* W1  = (const float*)d_in[4];
    const float* b1  = (const float*)d_in[5];
    const float* bng = (const float*)d_in[6];
    const float* bnb = (const float*)d_in[7];
    const float* bnm = (const float*)d_in[8];
    const float* bnv = (const float*)d_in[9];
    const float* W2  = (const float*)d_in[10];
    const float* b2  = (const float*)d_in[11];
    const float* W3  = (const float*)d_in[12];
    const float* b3  = (const float*)d_in[13];
    const float* fk  = (const float*)d_in[14];
    const float* fr  = (const float*)d_in[15];
    const float* fb  = (const float*)d_in[16];
    const float* bk  = (const float*)d_in[17];
    const float* br  = (const float*)d_in[18];
    const float* bbv = (const float*)d_in[19];
    const float* Wsh = (const float*)d_in[20];
    const float* bsh = (const float*)d_in[21];
    const float* Wsc = (const float*)d_in[22];
    const float* bsc = (const float*)d_in[23];
    const float* Wq  = (const float*)d_in[24];
    const float* bq  = (const float*)d_in[25];
    const float* dk  = (const float*)d_in[26];
    const float* dr  = (const float*)d_in[27];
    const float* db  = (const float*)d_in[28];
    const float* Wo  = (const float*)d_in[29];
    const float* bo  = (const float*)d_in[30];

    // ws: packed seq hi/lo u32 [B*T][8] (16.8 MB) + Y bf16 [B*T] (1.05 MB)
    unsigned int*   sqpk = (unsigned int*)d_ws;
    unsigned short* yv   = (unsigned short*)(sqpk + (size_t)BB * TT * 8);

    k_mlp2<<<768, 256, 0, stream>>>(X, Yp, lng, lnb, W1, b1, bng, bnb, bnm, bnv,
                                    W2, b2, W3, b3, sqpk, yv);
    k_rnn<<<BB / 16, 512, 0, stream>>>(sqpk, yv, fk, fr, fb, bk, br, bbv,
                                       Wsh, bsh, Wsc, bsc, Wq, bq, dk, dr, db, Wo, bo,
                                       (float*)d_out);
}

// Round 6
// 800.973 us; speedup vs baseline: 3.1299x; 1.4481x over previous
//
#include <hip/hip_runtime.h>
#include <math.h>

#define BB 4096
#define TT 128
#define FF 256
#define VV 32
#define LN_EPS 1e-3f

typedef __attribute__((ext_vector_type(8))) short short8;
typedef __attribute__((ext_vector_type(4))) float f32x4;

template <int M> struct IC { static constexpr int value = M; };

__device__ __forceinline__ float sigm(float x) {
    return __builtin_amdgcn_rcpf(1.0f + __builtin_amdgcn_exp2f(-1.442695041f * x));
}
__device__ __forceinline__ float tanhfast(float x) {
    float e = __builtin_amdgcn_exp2f(2.885390082f * x);
    return 1.0f - 2.0f * __builtin_amdgcn_rcpf(e + 1.0f);
}
__device__ __forceinline__ unsigned short f2bf(float f) {
    union { float f; unsigned u; } v; v.f = f;
    unsigned r = v.u + 0x7FFFu + ((v.u >> 16) & 1u);   // RNE
    return (unsigned short)(r >> 16);
}
__device__ __forceinline__ float bf2f(unsigned short h) {
    union { unsigned u; float f; } v; v.u = ((unsigned)h) << 16; return v.f;
}

// =================== Kernel 1: LN + MLP via MFMA -> frag-ready packed seq ===================
// Output per row: dwords 0..3 = bf16-hi pairs (f1,f0)(f3,f2)(f5,f4)(f7,f6), dwords 4..7 = lo pairs.
__global__ __launch_bounds__(256, 3) void k_mlp2(
    const float* __restrict__ X, const int* __restrict__ Yp,
    const float* __restrict__ lng, const float* __restrict__ lnb,
    const float* __restrict__ W1, const float* __restrict__ b1,
    const float* __restrict__ bng, const float* __restrict__ bnb,
    const float* __restrict__ bnm, const float* __restrict__ bnv,
    const float* __restrict__ W2, const float* __restrict__ b2,
    const float* __restrict__ W3, const float* __restrict__ b3,
    unsigned int* __restrict__ sqpk, unsigned short* __restrict__ yv)
{
    __shared__ unsigned short w1fh[8192], w1fl[8192];   // [ks][nt][lane][j]
    __shared__ unsigned short w2fh[512], w2fl[512];     // [lane][j]
    __shared__ unsigned short w3fh[512], w3fl[512];
    __shared__ float bD1[32], bnSs[32], bnBs[32], b2s[16], b3s[8];
    __shared__ float e1s[4][16][33];
    __shared__ float e2s[4][16][17];

    const int tid = threadIdx.x;
    for (int e = tid; e < 8192; e += 256) {
        int j = e & 7, lane = (e >> 3) & 63, nt = (e >> 9) & 1, ks = e >> 10;
        int c = ks * 32 + (lane >> 4) * 8 + j;
        int n = nt * 16 + (lane & 15);
        float v = lng[c] * W1[c * 32 + n];
        unsigned short hi = f2bf(v);
        w1fh[e] = hi; w1fl[e] = f2bf(v - bf2f(hi));
    }
    for (int e = tid; e < 512; e += 256) {
        int j = e & 7, lane = e >> 3;
        int k = (lane >> 4) * 8 + j, n = lane & 15;
        float v2 = W2[k * 16 + n];
        unsigned short h2 = f2bf(v2);
        w2fh[e] = h2; w2fl[e] = f2bf(v2 - bf2f(h2));
        float v3 = (k < 16 && n < 8) ? W3[k * 8 + n] : 0.f;
        unsigned short h3 = f2bf(v3);
        w3fh[e] = h3; w3fl[e] = f2bf(v3 - bf2f(h3));
    }
    if (tid < 32) {
        float a = b1[tid];
        for (int c2 = 0; c2 < 256; ++c2) a += lnb[c2] * W1[c2 * 32 + tid];
        bD1[tid] = a;
        float sc = bng[tid] * rsqrtf(bnv[tid] + LN_EPS);
        bnSs[tid] = sc; bnBs[tid] = bnb[tid] - bnm[tid] * sc;
    } else if (tid < 48) b2s[tid - 32] = b2[tid - 32];
    else if (tid < 56) b3s[tid - 48] = b3[tid - 48];
    __syncthreads();

    const int wv = tid >> 6, l = tid & 63;
    const int r = l & 15, q = l >> 4;
    const int ntiles = (BB * TT) / 16;   // 32768
    for (int tile = blockIdx.x * 4 + wv; tile < ntiles; tile += gridDim.x * 4) {
        const size_t rowbase = (size_t)tile * 16;
        const float* xrow = X + (rowbase + r) * FF + q * 8;
        float xd[64];
        #pragma unroll
        for (int ks = 0; ks < 8; ++ks) {
            float4 p0 = *(const float4*)(xrow + ks * 32);
            float4 p1 = *(const float4*)(xrow + ks * 32 + 4);
            xd[ks * 8 + 0] = p0.x; xd[ks * 8 + 1] = p0.y; xd[ks * 8 + 2] = p0.z; xd[ks * 8 + 3] = p0.w;
            xd[ks * 8 + 4] = p1.x; xd[ks * 8 + 5] = p1.y; xd[ks * 8 + 6] = p1.z; xd[ks * 8 + 7] = p1.w;
        }
        float s = 0.f, ss = 0.f;
        #pragma unroll
        for (int i = 0; i < 64; ++i) { s += xd[i]; ss += xd[i] * xd[i]; }
        s += __shfl_xor(s, 16);  s += __shfl_xor(s, 32);
        ss += __shfl_xor(ss, 16); ss += __shfl_xor(ss, 32);
        float mu = s * (1.0f / FF);
        float var = ss * (1.0f / FF) - mu * mu;
        float rs = rsqrtf(var + LN_EPS);

        f32x4 acc0 = {bD1[r], bD1[r], bD1[r], bD1[r]};
        f32x4 acc1 = {bD1[16 + r], bD1[16 + r], bD1[16 + r], bD1[16 + r]};
        #pragma unroll
        for (int ks = 0; ks < 8; ++ks) {
            short8 ah, al;
            #pragma unroll
            for (int j = 0; j < 8; ++j) {
                float xn = (xd[ks * 8 + j] - mu) * rs;
                unsigned short hi = f2bf(xn);
                ah[j] = (short)hi; al[j] = (short)f2bf(xn - bf2f(hi));
            }
            short8 bh0 = *(const short8*)&w1fh[((ks * 2 + 0) * 64 + l) * 8];
            short8 bl0 = *(const short8*)&w1fl[((ks * 2 + 0) * 64 + l) * 8];
            short8 bh1 = *(const short8*)&w1fh[((ks * 2 + 1) * 64 + l) * 8];
            short8 bl1 = *(const short8*)&w1fl[((ks * 2 + 1) * 64 + l) * 8];
            acc0 = __builtin_amdgcn_mfma_f32_16x16x32_bf16(ah, bh0, acc0, 0, 0, 0);
            acc0 = __builtin_amdgcn_mfma_f32_16x16x32_bf16(al, bh0, acc0, 0, 0, 0);
            acc0 = __builtin_amdgcn_mfma_f32_16x16x32_bf16(ah, bl0, acc0, 0, 0, 0);
            acc1 = __builtin_amdgcn_mfma_f32_16x16x32_bf16(ah, bh1, acc1, 0, 0, 0);
            acc1 = __builtin_amdgcn_mfma_f32_16x16x32_bf16(al, bh1, acc1, 0, 0, 0);
            acc1 = __builtin_amdgcn_mfma_f32_16x16x32_bf16(ah, bl1, acc1, 0, 0, 0);
        }
        #pragma unroll
        for (int i = 0; i < 4; ++i) {
            int row = q * 4 + i;
            float z0 = fmaxf(acc0[i], 0.f) * bnSs[r] + bnBs[r];
            float z1 = fmaxf(acc1[i], 0.f) * bnSs[16 + r] + bnBs[16 + r];
            e1s[wv][row][r] = z0;
            e1s[wv][row][16 + r] = z1;
        }
        __builtin_amdgcn_wave_barrier();

        short8 a2h, a2l;
        #pragma unroll
        for (int j = 0; j < 8; ++j) {
            float v = e1s[wv][r][q * 8 + j];
            unsigned short hi = f2bf(v);
            a2h[j] = (short)hi; a2l[j] = (short)f2bf(v - bf2f(hi));
        }
        f32x4 acc2 = {b2s[r], b2s[r], b2s[r], b2s[r]};
        {
            short8 bh = *(const short8*)&w2fh[l * 8];
            short8 bl = *(const short8*)&w2fl[l * 8];
            acc2 = __builtin_amdgcn_mfma_f32_16x16x32_bf16(a2h, bh, acc2, 0, 0, 0);
            acc2 = __builtin_amdgcn_mfma_f32_16x16x32_bf16(a2l, bh, acc2, 0, 0, 0);
            acc2 = __builtin_amdgcn_mfma_f32_16x16x32_bf16(a2h, bl, acc2, 0, 0, 0);
        }
        #pragma unroll
        for (int i = 0; i < 4; ++i) e2s[wv][q * 4 + i][r] = fmaxf(acc2[i], 0.f);
        __builtin_amdgcn_wave_barrier();

        short8 a3h = (short8){0,0,0,0,0,0,0,0}, a3l = (short8){0,0,0,0,0,0,0,0};
        if (q < 2) {
            #pragma unroll
            for (int j = 0; j < 8; ++j) {
                float v = e2s[wv][r][q * 8 + j];
                unsigned short hi = f2bf(v);
                a3h[j] = (short)hi; a3l[j] = (short)f2bf(v - bf2f(hi));
            }
        }
        float b3v = (r < 8) ? b3s[r] : 0.f;
        f32x4 acc3 = {b3v, b3v, b3v, b3v};
        {
            short8 bh = *(const short8*)&w3fh[l * 8];
            short8 bl = *(const short8*)&w3fl[l * 8];
            acc3 = __builtin_amdgcn_mfma_f32_16x16x32_bf16(a3h, bh, acc3, 0, 0, 0);
            acc3 = __builtin_amdgcn_mfma_f32_16x16x32_bf16(a3l, bh, acc3, 0, 0, 0);
            acc3 = __builtin_amdgcn_mfma_f32_16x16x32_bf16(a3h, bl, acc3, 0, 0, 0);
        }
        // frag-ready store: even r -> hi-pair dword, odd r -> lo-pair dword
        if (r < 8) {
            #pragma unroll
            for (int i = 0; i < 4; ++i) {
                size_t grow = rowbase + q * 4 + i;
                float e3 = fmaxf(acc3[i], 0.f);
                unsigned short bfh = f2bf(e3);
                unsigned short bfe = f2bf(e3 - bf2f(bfh));
                unsigned int wself = ((unsigned)bfh << 16) | (unsigned)bfe;
                unsigned int wnbr = __shfl_xor(wself, 1);
                unsigned int outw = (r & 1) ? ((wself << 16) | (wnbr & 0xFFFFu))
                                            : ((wnbr & 0xFFFF0000u) | (wself >> 16));
                sqpk[grow * 8 + (r >> 1) + ((r & 1) ? 4 : 0)] = outw;
            }
        } else if (r == 8) {
            #pragma unroll
            for (int i = 0; i < 4; ++i) {
                size_t grow = rowbase + q * 4 + i;
                yv[grow] = f2bf((float)Yp[grow]);
            }
        }
        __builtin_amdgcn_wave_barrier();
    }
}

// ====== Kernel 2: fused BiLSTM (3-pass) + exact attention + decoder + output ======
// LDS arena offsets (bytes)
#define A_SEQ   0u        // u32 [128][2][16][4]   = 65536  (plane 0 = hi, 1 = lo)
#define A_YV    65536u    // u16 [128][16]         = 4096
#define A_HP    69632u    // u32 [2][2][16][68]    = 17408  (hi pairs 0..31, lo pairs 32..63, pad)
#define A_SGRID 87040u    // f32 [2][16][128] = 16384; overlays hfin/cfin [16][128]x2 and zd [16][256]
#define A_SH    103424u   // f32 [16][64]
#define A_SC    107520u   // f32 [16][64]
#define A_Q     111616u   // f32 [16][128]; overlays pT [128][16]
#define A_ATT   119808u   // f32 [16][128]; overlays hd [16][64]
#define A_L     128000u   // f32 [16]
#define A_SZ    128064u

__global__ __launch_bounds__(512, 1) void k_rnn(
    const unsigned int* __restrict__ g_sqpk, const unsigned short* __restrict__ g_yv,
    const float* __restrict__ fk, const float* __restrict__ fr, const float* __restrict__ fb,
    const float* __restrict__ bk, const float* __restrict__ br, const float* __restrict__ bbv,
    const float* __restrict__ Wsh, const float* __restrict__ bsh,
    const float* __restrict__ Wsc, const float* __restrict__ bsc,
    const float* __restrict__ Wq,  const float* __restrict__ bq,
    const float* __restrict__ dk,  const float* __restrict__ dr, const float* __restrict__ db,
    const float* __restrict__ Wo,  const float* __restrict__ bo,
    float* __restrict__ out)
{
    __shared__ __align__(16) unsigned char arena[A_SZ];
    unsigned int*  seqU  = (unsigned int*)(arena + A_SEQ);
    unsigned short* yvS  = (unsigned short*)(arena + A_YV);
    unsigned int*  hpackU = (unsigned int*)(arena + A_HP);
    float* sgridF = (float*)(arena + A_SGRID);
    float* hfinL  = (float*)(arena + A_SGRID);
    float* cfinL  = hfinL + 2048;
    float* zdS    = (float*)(arena + A_SGRID);
    float* shS    = (float*)(arena + A_SH);
    float* scS    = (float*)(arena + A_SC);
    float* qS     = (float*)(arena + A_Q);
    float* pT     = (float*)(arena + A_Q);
    float* attS   = (float*)(arena + A_ATT);
    float* hdS    = (float*)(arena + A_ATT);
    float* lS     = (float*)(arena + A_L);

    const int tid = threadIdx.x;
    const int sbase = blockIdx.x * 16;
    const int wv = tid >> 6, l = tid & 63;
    const int d = wv >> 2, w = wv & 3;
    const int r = l & 15, q = l >> 4;
    const int u = (w << 4) + r;

    // stage seq (frag-ready planes) + y
    for (int i = tid; i < 16 * TT * 8; i += 512) {
        int smp = i >> 10;
        int rem = i & 1023;
        int t = rem >> 3, j = rem & 7;
        unsigned int v = g_sqpk[(size_t)(sbase + smp) * (TT * 8) + rem];
        seqU[((t * 2 + (j >> 2)) * 16 + smp) * 4 + (j & 3)] = v;
    }
    for (int i = tid; i < 16 * TT; i += 512) {
        int smp = i >> 7, t = i & 127;
        yvS[t * 16 + smp] = g_yv[(size_t)(sbase + smp) * TT + t];
    }

    // recurrence B fragments (layout proven in round 4)
    const float* Wr = d ? br : fr;
    const float* Wk = d ? bk : fk;
    const float* Bz = d ? bbv : fb;
    short8 Bh[3][4], Bl[3][4];
    float bz[4];
    #pragma unroll
    for (int g = 0; g < 4; ++g) {
        int col = (g << 6) + u;
        bz[g] = Bz[col];
        #pragma unroll
        for (int kt = 0; kt < 3; ++kt) {
            #pragma unroll
            for (int j = 0; j < 8; ++j) {
                int kg = kt * 32 + q * 8 + j;
                float v = (kg < 64) ? Wr[kg * 256 + col]
                        : (kg < 73) ? Wk[(kg - 64) * 256 + col] : 0.f;
                unsigned short hi = f2bf(v);
                Bh[kt][g][j] = (short)hi;
                Bl[kt][g][j] = (short)f2bf(v - bf2f(hi));
            }
        }
    }
    short8 Bq0h = (short8){0,0,0,0,0,0,0,0}, Bq1h = (short8){0,0,0,0,0,0,0,0};

    // precomputed addresses
    const unsigned int* hrd0 = hpackU + (d * 16 + r) * 68 + q * 4;          // buf 0 read base
    const unsigned int* hrd1 = hrd0 + 2176;                                  // buf 1 (+2*16*68)
    const int wofs = w * 8 + (r >> 1) + ((r & 1) ? 32 : 0);                  // producer dword in row
    __syncthreads();

    auto run_phase = [&](auto mode_c) {
        constexpr int mode = decltype(mode_c)::value;
        for (int i = tid; i < 4352; i += 512) hpackU[i] = 0u;
        float c4[4] = {0.f, 0.f, 0.f, 0.f};
        float aacc[4] = {0.f, 0.f, 0.f, 0.f};
        __syncthreads();
        for (int t = 0; t < TT; ++t) {
            const int ts = d ? (TT - 1 - t) : t;
            const int buf = t & 1;
            const unsigned int* hp = buf ? hrd1 : hrd0;
            short8 A0h = *(const short8*)(hp);
            short8 A1h = *(const short8*)(hp + 16);
            short8 A0l = *(const short8*)(hp + 32);
            short8 A1l = *(const short8*)(hp + 48);
            short8 A2h = (short8){0,0,0,0,0,0,0,0};
            short8 A2l = (short8){0,0,0,0,0,0,0,0};
            if (q == 0) {
                const unsigned int* sp = seqU + (ts * 32 + r) * 4;   // plane stride 16*4=64
                A2h = *(const short8*)sp;
                A2l = *(const short8*)(sp + 64);
            } else if (q == 1) {
                A2h[0] = (short)yvS[ts * 16 + r];
            }
            if constexpr (mode == 1) {
                if (w == 0 && t > 0) {       // score of previous step's h
                    f32x4 sa = {0.f, 0.f, 0.f, 0.f};
                    sa = __builtin_amdgcn_mfma_f32_16x16x32_bf16(A0h, Bq0h, sa, 0, 0, 0);
                    sa = __builtin_amdgcn_mfma_f32_16x16x32_bf16(A1h, Bq1h, sa, 0, 0, 0);
                    if (q == (r >> 2)) {
                        int tp = d ? (TT - t) : (t - 1);
                        sgridF[(d * 16 + r) * 128 + tp] = sa[r & 3];
                    }
                }
            }
            f32x4 z[4];
            #pragma unroll
            for (int g = 0; g < 4; ++g) {
                f32x4 acc = {bz[g], bz[g], bz[g], bz[g]};
                acc = __builtin_amdgcn_mfma_f32_16x16x32_bf16(A0h, Bh[0][g], acc, 0, 0, 0);
                acc = __builtin_amdgcn_mfma_f32_16x16x32_bf16(A0l, Bh[0][g], acc, 0, 0, 0);
                acc = __builtin_amdgcn_mfma_f32_16x16x32_bf16(A0h, Bl[0][g], acc, 0, 0, 0);
                acc = __builtin_amdgcn_mfma_f32_16x16x32_bf16(A1h, Bh[1][g], acc, 0, 0, 0);
                acc = __builtin_amdgcn_mfma_f32_16x16x32_bf16(A1l, Bh[1][g], acc, 0, 0, 0);
                acc = __builtin_amdgcn_mfma_f32_16x16x32_bf16(A1h, Bl[1][g], acc, 0, 0, 0);
                acc = __builtin_amdgcn_mfma_f32_16x16x32_bf16(A2h, Bh[2][g], acc, 0, 0, 0);
                acc = __builtin_amdgcn_mfma_f32_16x16x32_bf16(A2l, Bh[2][g], acc, 0, 0, 0);
                acc = __builtin_amdgcn_mfma_f32_16x16x32_bf16(A2h, Bl[2][g], acc, 0, 0, 0);
                z[g] = acc;
            }
            const int nbase = ((buf ^ 1) * 2 + d) * 16;
            #pragma unroll
            for (int i = 0; i < 4; ++i) {
                float zi = z[0][i], zf = z[1][i], zg = z[2][i], zo = z[3][i];
                float cc = sigm(zf) * c4[i] + sigm(zi) * tanhfast(zg);
                float hh = sigm(zo) * tanhfast(cc);
                c4[i] = cc;
                int smp = (q << 2) + i;
                // pack bf16 hi/lo pair with neighbor lane (unit u^1), frag-ready
                unsigned short bfh = f2bf(hh);
                unsigned short bfe = f2bf(hh - bf2f(bfh));
                unsigned int wself = ((unsigned)bfh << 16) | (unsigned)bfe;
                unsigned int wnbr = __shfl_xor(wself, 1);
                unsigned int outw = (r & 1) ? ((wself << 16) | (wnbr & 0xFFFFu))
                                            : ((wnbr & 0xFFFF0000u) | (wself >> 16));
                hpackU[(nbase + smp) * 68 + wofs] = outw;
                if constexpr (mode == 2) aacc[i] += pT[ts * 16 + smp] * hh;
                if constexpr (mode == 0) {
                    if (t == TT - 1) {
                        hfinL[smp * 128 + (d << 6) + u] = hh;
                        cfinL[smp * 128 + (d << 6) + u] = cc;
                    }
                }
            }
            __syncthreads();
        }
        if constexpr (mode == 1) {   // epilogue: score of final h (in buf 0)
            if (w == 0) {
                short8 A0h = *(const short8*)(hrd0);
                short8 A1h = *(const short8*)(hrd0 + 16);
                f32x4 sa = {0.f, 0.f, 0.f, 0.f};
                sa = __builtin_amdgcn_mfma_f32_16x16x32_bf16(A0h, Bq0h, sa, 0, 0, 0);
                sa = __builtin_amdgcn_mfma_f32_16x16x32_bf16(A1h, Bq1h, sa, 0, 0, 0);
                if (q == (r >> 2)) {
                    int tp = d ? 0 : (TT - 1);
                    sgridF[(d * 16 + r) * 128 + tp] = sa[r & 3];
                }
            }
            __syncthreads();
        }
        if constexpr (mode == 2) {
            #pragma unroll
            for (int i = 0; i < 4; ++i) {
                int smp = (q << 2) + i;
                attS[smp * 128 + (d << 6) + u] = aacc[i] / lS[smp];
            }
            __syncthreads();
        }
    };

    // ---- P1: recurrence -> finals ----
    run_phase(IC<0>{});
    for (int o = tid; o < 2048; o += 512) {
        int kind = o >> 10, smp = (o >> 6) & 15, uu = o & 63;
        const float* src = kind ? (cfinL + smp * 128) : (hfinL + smp * 128);
        const float* Wm = kind ? Wsc : Wsh;
        float a = kind ? bsc[uu] : bsh[uu];
        #pragma unroll 4
        for (int j = 0; j < 128; ++j) a += src[j] * Wm[j * 64 + uu];
        (kind ? scS : shS)[smp * 64 + uu] = a;
    }
    __syncthreads();
    for (int o = tid; o < 2048; o += 512) {
        int smp = o >> 7, dd = o & 127;
        float a = bq[dd];
        #pragma unroll 4
        for (int j = 0; j < 64; ++j) a += shS[smp * 64 + j] * Wq[j * 128 + dd];
        qS[smp * 128 + dd] = a;
    }
    __syncthreads();
    if (w == 0) {   // query B-fragments (col = sample, k = unit)
        #pragma unroll
        for (int j = 0; j < 8; ++j) {
            Bq0h[j] = (short)f2bf(qS[r * 128 + (d << 6) + q * 8 + j]);
            Bq1h[j] = (short)f2bf(qS[r * 128 + (d << 6) + 32 + q * 8 + j]);
        }
    }
    __syncthreads();

    // ---- P2: recurrence + score halves ----
    run_phase(IC<1>{});
    {
        int smp = tid >> 5, sl = tid & 31;
        float sv[4];
        #pragma unroll
        for (int p = 0; p < 4; ++p) {
            int t = sl + 32 * p;
            sv[p] = sgridF[smp * 128 + t] + sgridF[(16 + smp) * 128 + t];
        }
        float m = fmaxf(fmaxf(sv[0], sv[1]), fmaxf(sv[2], sv[3]));
        #pragma unroll
        for (int mk = 1; mk < 32; mk <<= 1) m = fmaxf(m, __shfl_xor(m, mk));
        float lsum = 0.f;
        #pragma unroll
        for (int p = 0; p < 4; ++p) lsum += __expf(sv[p] - m);
        #pragma unroll
        for (int mk = 1; mk < 32; mk <<= 1) lsum += __shfl_xor(lsum, mk);
        __syncthreads();              // sgrid reads done; pT overwrites qS region
        #pragma unroll
        for (int p = 0; p < 4; ++p) pT[(sl + 32 * p) * 16 + smp] = __expf(sv[p] - m);
        if (sl == 0) lS[smp] = lsum;
    }
    __syncthreads();

    // ---- P3: recurrence + weighted accumulation -> attS ----
    run_phase(IC<2>{});

    // ---- head: decoder + output softmax ----
    for (int o = tid; o < 4096; o += 512) {
        int smp = o >> 8, col = o & 255;
        float a = db[col];
        #pragma unroll 4
        for (int j = 0; j < 128; ++j) a += attS[smp * 128 + j] * dk[j * 256 + col];
        #pragma unroll 4
        for (int j = 0; j < 64; ++j)  a += shS[smp * 64 + j] * dr[j * 256 + col];
        zdS[smp * 256 + col] = a;
    }
    __syncthreads();
    for (int o = tid; o < 1024; o += 512) {
        int smp = o >> 6, uu = o & 63;
        float zi = zdS[smp * 256 + uu], zf = zdS[smp * 256 + 64 + uu];
        float zg = zdS[smp * 256 + 128 + uu], zo = zdS[smp * 256 + 192 + uu];
        float cc = sigm(zf) * scS[smp * 64 + uu] + sigm(zi) * tanhfast(zg);
        hdS[smp * 64 + uu] = sigm(zo) * tanhfast(cc);
    }
    __syncthreads();
    {
        int smp = tid >> 5, v = tid & 31;
        float a = bo[v];
        #pragma unroll 4
        for (int j = 0; j < 64; ++j) a += hdS[smp * 64 + j] * Wo[j * 32 + v];
        float m = a;
        #pragma unroll
        for (int mk = 1; mk < 32; mk <<= 1) m = fmaxf(m, __shfl_xor(m, mk));
        float e = __expf(a - m);
        float s2 = e;
        #pragma unroll
        for (int mk = 1; mk < 32; mk <<= 1) s2 += __shfl_xor(s2, mk);
        out[(size_t)(sbase + smp) * VV + v] = e / s2;
    }
}

extern "C" void kernel_launch(void* const* d_in, const int* in_sizes, int n_in,
                              void* d_out, int out_size, void* d_ws, size_t ws_size,
                              hipStream_t stream) {
    const float* X   = (const float*)d_in[0];
    const int*   Yp  = (const int*)d_in[1];
    const float* lng = (const float*)d_in[2];
    const float* lnb = (const float*)d_in[3];
    const float* W1  = (const float*)d_in[4];
    const float* b1  = (const float*)d_in[5];
    const float* bng = (const float*)d_in[6];
    const float* bnb = (const float*)d_in[7];
    const float* bnm = (const float*)d_in[8];
    const float* bnv = (const float*)d_in[9];
    const float* W2  = (const float*)d_in[10];
    const float* b2  = (const float*)d_in[11];
    const float* W3  = (const float*)d_in[12];
    const float* b3  = (const float*)d_in[13];
    const float* fk  = (const float*)d_in[14];
    const float* fr  = (const float*)d_in[15];
    const float* fb  = (const float*)d_in[16];
    const float* bk  = (const float*)d_in[17];
    const float* br  = (const float*)d_in[18];
    const float* bbv = (const float*)d_in[19];
    const float* Wsh = (const float*)d_in[20];
    const float* bsh = (const float*)d_in[21];
    const float* Wsc = (const float*)d_in[22];
    const float* bsc = (const float*)d_in[23];
    const float* Wq  = (const float*)d_in[24];
    const float* bq  = (const float*)d_in[25];
    const float* dk  = (const float*)d_in[26];
    const float* dr  = (const float*)d_in[27];
    const float* db  = (const float*)d_in[28];
    const float* Wo  = (const float*)d_in[29];
    const float* bo  = (const float*)d_in[30];

    // ws: packed seq u32 [B*T][8] (16.8 MB) + Y bf16 [B*T] (1.05 MB)
    unsigned int*   sqpk = (unsigned int*)d_ws;
    unsigned short* yv   = (unsigned short*)(sqpk + (size_t)BB * TT * 8);

    k_mlp2<<<768, 256, 0, stream>>>(X, Yp, lng, lnb, W1, b1, bng, bnb, bnm, bnv,
                                    W2, b2, W3, b3, sqpk, yv);
    k_rnn<<<BB / 16, 512, 0, stream>>>(sqpk, yv, fk, fr, fb, bk, br, bbv,
                                       Wsh, bsh, Wsc, bsc, Wq, bq, dk, dr, db, Wo, bo,
                                       (float*)d_out);
}

// Round 7
// 504.741 us; speedup vs baseline: 4.9668x; 1.5869x over previous
//
#include <hip/hip_runtime.h>
#include <math.h>

#define BB 4096
#define TT 128
#define FF 256
#define VV 32
#define LN_EPS 1e-3f

typedef __attribute__((ext_vector_type(8))) short short8;
typedef __attribute__((ext_vector_type(4))) float f32x4;

template <int M> struct IC { static constexpr int value = M; };

__device__ __forceinline__ float sigm(float x) {
    return __builtin_amdgcn_rcpf(1.0f + __builtin_amdgcn_exp2f(-1.442695041f * x));
}
__device__ __forceinline__ float tanhfast(float x) {
    float e = __builtin_amdgcn_exp2f(2.885390082f * x);
    return 1.0f - 2.0f * __builtin_amdgcn_rcpf(e + 1.0f);
}
__device__ __forceinline__ unsigned short f2bf(float f) {
    union { float f; unsigned u; } v; v.f = f;
    unsigned r = v.u + 0x7FFFu + ((v.u >> 16) & 1u);   // RNE
    return (unsigned short)(r >> 16);
}
__device__ __forceinline__ float bf2f(unsigned short h) {
    union { unsigned u; float f; } v; v.u = ((unsigned)h) << 16; return v.f;
}

// =================== Kernel 1: LN + MLP via MFMA -> frag-ready packed seq ===================
__global__ __launch_bounds__(256, 3) void k_mlp2(
    const float* __restrict__ X, const int* __restrict__ Yp,
    const float* __restrict__ lng, const float* __restrict__ lnb,
    const float* __restrict__ W1, const float* __restrict__ b1,
    const float* __restrict__ bng, const float* __restrict__ bnb,
    const float* __restrict__ bnm, const float* __restrict__ bnv,
    const float* __restrict__ W2, const float* __restrict__ b2,
    const float* __restrict__ W3, const float* __restrict__ b3,
    unsigned int* __restrict__ sqpk, unsigned short* __restrict__ yv)
{
    __shared__ unsigned short w1fh[8192], w1fl[8192];
    __shared__ unsigned short w2fh[512], w2fl[512];
    __shared__ unsigned short w3fh[512], w3fl[512];
    __shared__ float bD1[32], bnSs[32], bnBs[32], b2s[16], b3s[8];
    __shared__ float e1s[4][16][33];
    __shared__ float e2s[4][16][17];

    const int tid = threadIdx.x;
    for (int e = tid; e < 8192; e += 256) {
        int j = e & 7, lane = (e >> 3) & 63, nt = (e >> 9) & 1, ks = e >> 10;
        int c = ks * 32 + (lane >> 4) * 8 + j;
        int n = nt * 16 + (lane & 15);
        float v = lng[c] * W1[c * 32 + n];
        unsigned short hi = f2bf(v);
        w1fh[e] = hi; w1fl[e] = f2bf(v - bf2f(hi));
    }
    for (int e = tid; e < 512; e += 256) {
        int j = e & 7, lane = e >> 3;
        int k = (lane >> 4) * 8 + j, n = lane & 15;
        float v2 = W2[k * 16 + n];
        unsigned short h2 = f2bf(v2);
        w2fh[e] = h2; w2fl[e] = f2bf(v2 - bf2f(h2));
        float v3 = (k < 16 && n < 8) ? W3[k * 8 + n] : 0.f;
        unsigned short h3 = f2bf(v3);
        w3fh[e] = h3; w3fl[e] = f2bf(v3 - bf2f(h3));
    }
    if (tid < 32) {
        float a = b1[tid];
        for (int c2 = 0; c2 < 256; ++c2) a += lnb[c2] * W1[c2 * 32 + tid];
        bD1[tid] = a;
        float sc = bng[tid] * rsqrtf(bnv[tid] + LN_EPS);
        bnSs[tid] = sc; bnBs[tid] = bnb[tid] - bnm[tid] * sc;
    } else if (tid < 48) b2s[tid - 32] = b2[tid - 32];
    else if (tid < 56) b3s[tid - 48] = b3[tid - 48];
    __syncthreads();

    const int wv = tid >> 6, l = tid & 63;
    const int r = l & 15, q = l >> 4;
    const int ntiles = (BB * TT) / 16;
    for (int tile = blockIdx.x * 4 + wv; tile < ntiles; tile += gridDim.x * 4) {
        const size_t rowbase = (size_t)tile * 16;
        const float* xrow = X + (rowbase + r) * FF + q * 8;
        float xd[64];
        #pragma unroll
        for (int ks = 0; ks < 8; ++ks) {
            float4 p0 = *(const float4*)(xrow + ks * 32);
            float4 p1 = *(const float4*)(xrow + ks * 32 + 4);
            xd[ks * 8 + 0] = p0.x; xd[ks * 8 + 1] = p0.y; xd[ks * 8 + 2] = p0.z; xd[ks * 8 + 3] = p0.w;
            xd[ks * 8 + 4] = p1.x; xd[ks * 8 + 5] = p1.y; xd[ks * 8 + 6] = p1.z; xd[ks * 8 + 7] = p1.w;
        }
        float s = 0.f, ss = 0.f;
        #pragma unroll
        for (int i = 0; i < 64; ++i) { s += xd[i]; ss += xd[i] * xd[i]; }
        s += __shfl_xor(s, 16);  s += __shfl_xor(s, 32);
        ss += __shfl_xor(ss, 16); ss += __shfl_xor(ss, 32);
        float mu = s * (1.0f / FF);
        float var = ss * (1.0f / FF) - mu * mu;
        float rs = rsqrtf(var + LN_EPS);

        f32x4 acc0 = {bD1[r], bD1[r], bD1[r], bD1[r]};
        f32x4 acc1 = {bD1[16 + r], bD1[16 + r], bD1[16 + r], bD1[16 + r]};
        #pragma unroll
        for (int ks = 0; ks < 8; ++ks) {
            short8 ah, al;
            #pragma unroll
            for (int j = 0; j < 8; ++j) {
                float xn = (xd[ks * 8 + j] - mu) * rs;
                unsigned short hi = f2bf(xn);
                ah[j] = (short)hi; al[j] = (short)f2bf(xn - bf2f(hi));
            }
            short8 bh0 = *(const short8*)&w1fh[((ks * 2 + 0) * 64 + l) * 8];
            short8 bl0 = *(const short8*)&w1fl[((ks * 2 + 0) * 64 + l) * 8];
            short8 bh1 = *(const short8*)&w1fh[((ks * 2 + 1) * 64 + l) * 8];
            short8 bl1 = *(const short8*)&w1fl[((ks * 2 + 1) * 64 + l) * 8];
            acc0 = __builtin_amdgcn_mfma_f32_16x16x32_bf16(ah, bh0, acc0, 0, 0, 0);
            acc0 = __builtin_amdgcn_mfma_f32_16x16x32_bf16(al, bh0, acc0, 0, 0, 0);
            acc0 = __builtin_amdgcn_mfma_f32_16x16x32_bf16(ah, bl0, acc0, 0, 0, 0);
            acc1 = __builtin_amdgcn_mfma_f32_16x16x32_bf16(ah, bh1, acc1, 0, 0, 0);
            acc1 = __builtin_amdgcn_mfma_f32_16x16x32_bf16(al, bh1, acc1, 0, 0, 0);
            acc1 = __builtin_amdgcn_mfma_f32_16x16x32_bf16(ah, bl1, acc1, 0, 0, 0);
        }
        #pragma unroll
        for (int i = 0; i < 4; ++i) {
            int row = q * 4 + i;
            float z0 = fmaxf(acc0[i], 0.f) * bnSs[r] + bnBs[r];
            float z1 = fmaxf(acc1[i], 0.f) * bnSs[16 + r] + bnBs[16 + r];
            e1s[wv][row][r] = z0;
            e1s[wv][row][16 + r] = z1;
        }
        __builtin_amdgcn_wave_barrier();

        short8 a2h, a2l;
        #pragma unroll
        for (int j = 0; j < 8; ++j) {
            float v = e1s[wv][r][q * 8 + j];
            unsigned short hi = f2bf(v);
            a2h[j] = (short)hi; a2l[j] = (short)f2bf(v - bf2f(hi));
        }
        f32x4 acc2 = {b2s[r], b2s[r], b2s[r], b2s[r]};
        {
            short8 bh = *(const short8*)&w2fh[l * 8];
            short8 bl = *(const short8*)&w2fl[l * 8];
            acc2 = __builtin_amdgcn_mfma_f32_16x16x32_bf16(a2h, bh, acc2, 0, 0, 0);
            acc2 = __builtin_amdgcn_mfma_f32_16x16x32_bf16(a2l, bh, acc2, 0, 0, 0);
            acc2 = __builtin_amdgcn_mfma_f32_16x16x32_bf16(a2h, bl, acc2, 0, 0, 0);
        }
        #pragma unroll
        for (int i = 0; i < 4; ++i) e2s[wv][q * 4 + i][r] = fmaxf(acc2[i], 0.f);
        __builtin_amdgcn_wave_barrier();

        short8 a3h = (short8){0,0,0,0,0,0,0,0}, a3l = (short8){0,0,0,0,0,0,0,0};
        if (q < 2) {
            #pragma unroll
            for (int j = 0; j < 8; ++j) {
                float v = e2s[wv][r][q * 8 + j];
                unsigned short hi = f2bf(v);
                a3h[j] = (short)hi; a3l[j] = (short)f2bf(v - bf2f(hi));
            }
        }
        float b3v = (r < 8) ? b3s[r] : 0.f;
        f32x4 acc3 = {b3v, b3v, b3v, b3v};
        {
            short8 bh = *(const short8*)&w3fh[l * 8];
            short8 bl = *(const short8*)&w3fl[l * 8];
            acc3 = __builtin_amdgcn_mfma_f32_16x16x32_bf16(a3h, bh, acc3, 0, 0, 0);
            acc3 = __builtin_amdgcn_mfma_f32_16x16x32_bf16(a3l, bh, acc3, 0, 0, 0);
            acc3 = __builtin_amdgcn_mfma_f32_16x16x32_bf16(a3h, bl, acc3, 0, 0, 0);
        }
        if (r < 8) {
            #pragma unroll
            for (int i = 0; i < 4; ++i) {
                size_t grow = rowbase + q * 4 + i;
                float e3 = fmaxf(acc3[i], 0.f);
                unsigned short bfh = f2bf(e3);
                unsigned short bfe = f2bf(e3 - bf2f(bfh));
                unsigned int wself = ((unsigned)bfh << 16) | (unsigned)bfe;
                unsigned int wnbr = __shfl_xor(wself, 1);
                unsigned int outw = (r & 1) ? ((wself << 16) | (wnbr & 0xFFFFu))
                                            : ((wnbr & 0xFFFF0000u) | (wself >> 16));
                sqpk[grow * 8 + (r >> 1) + ((r & 1) ? 4 : 0)] = outw;
            }
        } else if (r == 8) {
            #pragma unroll
            for (int i = 0; i < 4; ++i) {
                size_t grow = rowbase + q * 4 + i;
                yv[grow] = f2bf((float)Yp[grow]);
            }
        }
        __builtin_amdgcn_wave_barrier();
    }
}

// ============ Kernel 2a (preferred): SINGLE-pass BiLSTM -> enc(bf16 global) + finals ============
#define R1_SEQ 0u
#define R1_YV  65536u
#define R1_HP  69632u     // u32 [2][2][16][68]
#define R1_SZ  87040u

__global__ __launch_bounds__(512, 1) void k_rnn1(
    const unsigned int* __restrict__ g_sqpk, const unsigned short* __restrict__ g_yv,
    const float* __restrict__ fk, const float* __restrict__ fr, const float* __restrict__ fb,
    const float* __restrict__ bk, const float* __restrict__ br, const float* __restrict__ bbv,
    unsigned int* __restrict__ enc,                       // chunk-local [csmp][T][64] dwords
    float* __restrict__ hfin, float* __restrict__ cfin,   // absolute [B][128]
    int s0)
{
    __shared__ __align__(16) unsigned char arena[R1_SZ];
    unsigned int*  seqU   = (unsigned int*)(arena + R1_SEQ);
    unsigned short* yvS   = (unsigned short*)(arena + R1_YV);
    unsigned int*  hpackU = (unsigned int*)(arena + R1_HP);

    const int tid = threadIdx.x;
    const int sbase = s0 + blockIdx.x * 16;
    const int wv = tid >> 6, l = tid & 63;
    const int d = wv >> 2, w = wv & 3;
    const int r = l & 15, q = l >> 4;
    const int u = (w << 4) + r;

    for (int i = tid; i < 16 * TT * 8; i += 512) {
        int smp = i >> 10;
        int rem = i & 1023;
        int t = rem >> 3, j = rem & 7;
        unsigned int v = g_sqpk[(size_t)(sbase + smp) * (TT * 8) + rem];
        seqU[((t * 2 + (j >> 2)) * 16 + smp) * 4 + (j & 3)] = v;
    }
    for (int i = tid; i < 16 * TT; i += 512) {
        int smp = i >> 7, t = i & 127;
        yvS[t * 16 + smp] = g_yv[(size_t)(sbase + smp) * TT + t];
    }

    const float* Wr = d ? br : fr;
    const float* Wk = d ? bk : fk;
    const float* Bz = d ? bbv : fb;
    short8 Bh[3][4], Bl[3][4];
    float bz[4];
    #pragma unroll
    for (int g = 0; g < 4; ++g) {
        int col = (g << 6) + u;
        bz[g] = Bz[col];
        #pragma unroll
        for (int kt = 0; kt < 3; ++kt) {
            #pragma unroll
            for (int j = 0; j < 8; ++j) {
                int kg = kt * 32 + q * 8 + j;
                float v = (kg < 64) ? Wr[kg * 256 + col]
                        : (kg < 73) ? Wk[(kg - 64) * 256 + col] : 0.f;
                unsigned short hi = f2bf(v);
                Bh[kt][g][j] = (short)hi;
                Bl[kt][g][j] = (short)f2bf(v - bf2f(hi));
            }
        }
    }

    const unsigned int* hrd0 = hpackU + (d * 16 + r) * 68 + q * 4;
    const unsigned int* hrd1 = hrd0 + 2176;
    const int wofs = w * 8 + (r >> 1) + ((r & 1) ? 32 : 0);
    // enc dword base (even-r lanes write): idx = ((blk16+smp)*TT + ts)*64 + d*32 + (u>>1)
    const int elb = ((blockIdx.x * 16 + q * 4) * TT) * 64 + d * 32 + (u >> 1);

    for (int i = tid; i < 4352; i += 512) hpackU[i] = 0u;
    float c4[4] = {0.f, 0.f, 0.f, 0.f};
    __syncthreads();

    for (int t = 0; t < TT; ++t) {
        const int ts = d ? (TT - 1 - t) : t;
        const int buf = t & 1;
        const unsigned int* hp = buf ? hrd1 : hrd0;
        short8 A0h = *(const short8*)(hp);
        short8 A1h = *(const short8*)(hp + 16);
        short8 A0l = *(const short8*)(hp + 32);
        short8 A1l = *(const short8*)(hp + 48);
        short8 A2h = (short8){0,0,0,0,0,0,0,0};
        short8 A2l = (short8){0,0,0,0,0,0,0,0};
        if (q == 0) {
            const unsigned int* sp = seqU + (ts * 32 + r) * 4;
            A2h = *(const short8*)sp;
            A2l = *(const short8*)(sp + 64);
        } else if (q == 1) {
            A2h[0] = (short)yvS[ts * 16 + r];
        }
        f32x4 z[4];
        #pragma unroll
        for (int g = 0; g < 4; ++g) {
            f32x4 acc = {bz[g], bz[g], bz[g], bz[g]};
            acc = __builtin_amdgcn_mfma_f32_16x16x32_bf16(A0h, Bh[0][g], acc, 0, 0, 0);
            acc = __builtin_amdgcn_mfma_f32_16x16x32_bf16(A0l, Bh[0][g], acc, 0, 0, 0);
            acc = __builtin_amdgcn_mfma_f32_16x16x32_bf16(A0h, Bl[0][g], acc, 0, 0, 0);
            acc = __builtin_amdgcn_mfma_f32_16x16x32_bf16(A1h, Bh[1][g], acc, 0, 0, 0);
            acc = __builtin_amdgcn_mfma_f32_16x16x32_bf16(A1l, Bh[1][g], acc, 0, 0, 0);
            acc = __builtin_amdgcn_mfma_f32_16x16x32_bf16(A1h, Bl[1][g], acc, 0, 0, 0);
            acc = __builtin_amdgcn_mfma_f32_16x16x32_bf16(A2h, Bh[2][g], acc, 0, 0, 0);
            acc = __builtin_amdgcn_mfma_f32_16x16x32_bf16(A2l, Bh[2][g], acc, 0, 0, 0);
            acc = __builtin_amdgcn_mfma_f32_16x16x32_bf16(A2h, Bl[2][g], acc, 0, 0, 0);
            z[g] = acc;
        }
        const int nbase = ((buf ^ 1) * 2 + d) * 16;
        #pragma unroll
        for (int i = 0; i < 4; ++i) {
            float zi = z[0][i], zf = z[1][i], zg = z[2][i], zo = z[3][i];
            float cc = sigm(zf) * c4[i] + sigm(zi) * tanhfast(zg);
            float hh = sigm(zo) * tanhfast(cc);
            c4[i] = cc;
            int smp = (q << 2) + i;
            unsigned short bfh = f2bf(hh);
            unsigned short bfe = f2bf(hh - bf2f(bfh));
            unsigned int wself = ((unsigned)bfh << 16) | (unsigned)bfe;
            unsigned int wnbr = __shfl_xor(wself, 1);
            unsigned int outw = (r & 1) ? ((wself << 16) | (wnbr & 0xFFFFu))
                                        : ((wnbr & 0xFFFF0000u) | (wself >> 16));
            hpackU[(nbase + smp) * 68 + wofs] = outw;
            if ((r & 1) == 0) enc[elb + i * (TT * 64) + ts * 64] = outw;  // hi-pair: units u,u+1
            if (t == TT - 1) {
                hfin[(size_t)(sbase + smp) * 128 + (d << 6) + u] = hh;
                cfin[(size_t)(sbase + smp) * 128 + (d << 6) + u] = cc;
            }
        }
        __syncthreads();
    }
}

// ------- Kernel 2b: per-sample attention + decoder + output softmax (round-4 proven) -------
__global__ __launch_bounds__(256, 4) void k_att(
    const unsigned short* __restrict__ enc,
    const float* __restrict__ hfin, const float* __restrict__ cfin,
    const float* __restrict__ Wsh, const float* __restrict__ bsh,
    const float* __restrict__ Wsc, const float* __restrict__ bsc,
    const float* __restrict__ Wq,  const float* __restrict__ bq,
    const float* __restrict__ dk,  const float* __restrict__ dr, const float* __restrict__ dbv,
    const float* __restrict__ Wo,  const float* __restrict__ bo,
    float* __restrict__ out, int s0)
{
    __shared__ unsigned short el[TT][136];
    __shared__ float st[128], ct[128], shS[64], scS[64], qS[128], pS[128], attS[128], zdS[256], hdS[64], red[8];

    int tid = threadIdx.x;
    int bloc = blockIdx.x;
    int s = s0 + bloc;

    for (int i = tid; i < TT * 16; i += 256) {
        int t = i >> 4, c = i & 15;
        *(short8*)&el[t][c * 8] = *(const short8*)&enc[(size_t)bloc * TT * 128 + t * 128 + c * 8];
    }
    if (tid < 128) { st[tid] = hfin[(size_t)s * 128 + tid]; ct[tid] = cfin[(size_t)s * 128 + tid]; }
    __syncthreads();

    if (tid < 128) {
        int uu = tid & 63;
        const float* Wm = (tid < 64) ? Wsh : Wsc;
        const float* sv = (tid < 64) ? st : ct;
        float a = (tid < 64) ? bsh[uu] : bsc[uu];
        #pragma unroll 4
        for (int j = 0; j < 128; ++j) a += sv[j] * Wm[j * 64 + uu];
        if (tid < 64) shS[uu] = a; else scS[uu] = a;
    }
    __syncthreads();
    if (tid < 128) {
        float a = bq[tid];
        #pragma unroll 4
        for (int uu = 0; uu < 64; ++uu) a += shS[uu] * Wq[uu * 128 + tid];
        qS[tid] = a;
    }
    __syncthreads();
    float sc_val = 0.f;
    int wvv = tid >> 6, lnn = tid & 63;
    if (tid < 128) {
        float a = 0.f;
        #pragma unroll 2
        for (int c = 0; c < 16; ++c) {
            short8 e8 = *(const short8*)&el[tid][c * 8];
            #pragma unroll
            for (int j2 = 0; j2 < 8; ++j2) a += qS[c * 8 + j2] * bf2f((unsigned short)e8[j2]);
        }
        sc_val = a;
        float m = a;
        #pragma unroll
        for (int mk = 1; mk < 64; mk <<= 1) m = fmaxf(m, __shfl_xor(m, mk));
        if (lnn == 0) red[wvv] = m;
    }
    __syncthreads();
    float gmax = fmaxf(red[0], red[1]);
    if (tid < 128) {
        float ev = expf(sc_val - gmax);
        pS[tid] = ev;
        float s2 = ev;
        #pragma unroll
        for (int mk = 1; mk < 64; mk <<= 1) s2 += __shfl_xor(s2, mk);
        if (lnn == 0) red[4 + wvv] = s2;
    }
    __syncthreads();
    float denom = red[4] + red[5];
    if (tid < 128) {
        float a = 0.f;
        #pragma unroll 4
        for (int t2 = 0; t2 < TT; ++t2) a += pS[t2] * bf2f(el[t2][tid]);
        attS[tid] = a / denom;
    }
    __syncthreads();
    if (tid < 256) {
        float a = dbv[tid];
        #pragma unroll 4
        for (int j = 0; j < 128; ++j) a += attS[j] * dk[j * 256 + tid];
        #pragma unroll 4
        for (int j = 0; j < 64; ++j)  a += shS[j] * dr[j * 256 + tid];
        zdS[tid] = a;
    }
    __syncthreads();
    if (tid < 64) {
        float zi = zdS[tid], zf = zdS[64 + tid], zg = zdS[128 + tid], zo = zdS[192 + tid];
        float cc = sigm(zf) * scS[tid] + sigm(zi) * tanhfast(zg);
        hdS[tid] = sigm(zo) * tanhfast(cc);
    }
    __syncthreads();
    if (tid < 32) {
        float a = bo[tid];
        #pragma unroll
        for (int uu = 0; uu < 64; ++uu) a += hdS[uu] * Wo[uu * 32 + tid];
        float m = a;
        #pragma unroll
        for (int mk = 1; mk < 32; mk <<= 1) m = fmaxf(m, __shfl_xor(m, mk));
        float e = expf(a - m);
        float s2 = e;
        #pragma unroll
        for (int mk = 1; mk < 32; mk <<= 1) s2 += __shfl_xor(s2, mk);
        out[(size_t)s * VV + tid] = e / s2;
    }
}

// ====== Kernel 2-fallback: fused 3-pass (round-6 proven, used when ws too small) ======
#define A_SEQ   0u
#define A_YV    65536u
#define A_HP    69632u
#define A_SGRID 87040u
#define A_SH    103424u
#define A_SC    107520u
#define A_Q     111616u
#define A_ATT   119808u
#define A_L     128000u
#define A_SZ    128064u

__global__ __launch_bounds__(512, 1) void k_rnn(
    const unsigned int* __restrict__ g_sqpk, const unsigned short* __restrict__ g_yv,
    const float* __restrict__ fk, const float* __restrict__ fr, const float* __restrict__ fb,
    const float* __restrict__ bk, const float* __restrict__ br, const float* __restrict__ bbv,
    const float* __restrict__ Wsh, const float* __restrict__ bsh,
    const float* __restrict__ Wsc, const float* __restrict__ bsc,
    const float* __restrict__ Wq,  const float* __restrict__ bq,
    const float* __restrict__ dk,  const float* __restrict__ dr, const float* __restrict__ db,
    const float* __restrict__ Wo,  const float* __restrict__ bo,
    float* __restrict__ out)
{
    __shared__ __align__(16) unsigned char arena[A_SZ];
    unsigned int*  seqU  = (unsigned int*)(arena + A_SEQ);
    unsigned short* yvS  = (unsigned short*)(arena + A_YV);
    unsigned int*  hpackU = (unsigned int*)(arena + A_HP);
    float* sgridF = (float*)(arena + A_SGRID);
    float* hfinL  = (float*)(arena + A_SGRID);
    float* cfinL  = hfinL + 2048;
    float* zdS    = (float*)(arena + A_SGRID);
    float* shS    = (float*)(arena + A_SH);
    float* scS    = (float*)(arena + A_SC);
    float* qS     = (float*)(arena + A_Q);
    float* pT     = (float*)(arena + A_Q);
    float* attS   = (float*)(arena + A_ATT);
    float* hdS    = (float*)(arena + A_ATT);
    float* lS     = (float*)(arena + A_L);

    const int tid = threadIdx.x;
    const int sbase = blockIdx.x * 16;
    const int wv = tid >> 6, l = tid & 63;
    const int d = wv >> 2, w = wv & 3;
    const int r = l & 15, q = l >> 4;
    const int u = (w << 4) + r;

    for (int i = tid; i < 16 * TT * 8; i += 512) {
        int smp = i >> 10;
        int rem = i & 1023;
        int t = rem >> 3, j = rem & 7;
        unsigned int v = g_sqpk[(size_t)(sbase + smp) * (TT * 8) + rem];
        seqU[((t * 2 + (j >> 2)) * 16 + smp) * 4 + (j & 3)] = v;
    }
    for (int i = tid; i < 16 * TT; i += 512) {
        int smp = i >> 7, t = i & 127;
        yvS[t * 16 + smp] = g_yv[(size_t)(sbase + smp) * TT + t];
    }

    const float* Wr = d ? br : fr;
    const float* Wk = d ? bk : fk;
    const float* Bz = d ? bbv : fb;
    short8 Bh[3][4], Bl[3][4];
    float bz[4];
    #pragma unroll
    for (int g = 0; g < 4; ++g) {
        int col = (g << 6) + u;
        bz[g] = Bz[col];
        #pragma unroll
        for (int kt = 0; kt < 3; ++kt) {
            #pragma unroll
            for (int j = 0; j < 8; ++j) {
                int kg = kt * 32 + q * 8 + j;
                float v = (kg < 64) ? Wr[kg * 256 + col]
                        : (kg < 73) ? Wk[(kg - 64) * 256 + col] : 0.f;
                unsigned short hi = f2bf(v);
                Bh[kt][g][j] = (short)hi;
                Bl[kt][g][j] = (short)f2bf(v - bf2f(hi));
            }
        }
    }
    short8 Bq0h = (short8){0,0,0,0,0,0,0,0}, Bq1h = (short8){0,0,0,0,0,0,0,0};

    const unsigned int* hrd0 = hpackU + (d * 16 + r) * 68 + q * 4;
    const unsigned int* hrd1 = hrd0 + 2176;
    const int wofs = w * 8 + (r >> 1) + ((r & 1) ? 32 : 0);
    __syncthreads();

    auto run_phase = [&](auto mode_c) {
        constexpr int mode = decltype(mode_c)::value;
        for (int i = tid; i < 4352; i += 512) hpackU[i] = 0u;
        float c4[4] = {0.f, 0.f, 0.f, 0.f};
        float aacc[4] = {0.f, 0.f, 0.f, 0.f};
        __syncthreads();
        for (int t = 0; t < TT; ++t) {
            const int ts = d ? (TT - 1 - t) : t;
            const int buf = t & 1;
            const unsigned int* hp = buf ? hrd1 : hrd0;
            short8 A0h = *(const short8*)(hp);
            short8 A1h = *(const short8*)(hp + 16);
            short8 A0l = *(const short8*)(hp + 32);
            short8 A1l = *(const short8*)(hp + 48);
            short8 A2h = (short8){0,0,0,0,0,0,0,0};
            short8 A2l = (short8){0,0,0,0,0,0,0,0};
            if (q == 0) {
                const unsigned int* sp = seqU + (ts * 32 + r) * 4;
                A2h = *(const short8*)sp;
                A2l = *(const short8*)(sp + 64);
            } else if (q == 1) {
                A2h[0] = (short)yvS[ts * 16 + r];
            }
            if constexpr (mode == 1) {
                if (w == 0 && t > 0) {
                    f32x4 sa = {0.f, 0.f, 0.f, 0.f};
                    sa = __builtin_amdgcn_mfma_f32_16x16x32_bf16(A0h, Bq0h, sa, 0, 0, 0);
                    sa = __builtin_amdgcn_mfma_f32_16x16x32_bf16(A1h, Bq1h, sa, 0, 0, 0);
                    if (q == (r >> 2)) {
                        int tp = d ? (TT - t) : (t - 1);
                        sgridF[(d * 16 + r) * 128 + tp] = sa[r & 3];
                    }
                }
            }
            f32x4 z[4];
            #pragma unroll
            for (int g = 0; g < 4; ++g) {
                f32x4 acc = {bz[g], bz[g], bz[g], bz[g]};
                acc = __builtin_amdgcn_mfma_f32_16x16x32_bf16(A0h, Bh[0][g], acc, 0, 0, 0);
                acc = __builtin_amdgcn_mfma_f32_16x16x32_bf16(A0l, Bh[0][g], acc, 0, 0, 0);
                acc = __builtin_amdgcn_mfma_f32_16x16x32_bf16(A0h, Bl[0][g], acc, 0, 0, 0);
                acc = __builtin_amdgcn_mfma_f32_16x16x32_bf16(A1h, Bh[1][g], acc, 0, 0, 0);
                acc = __builtin_amdgcn_mfma_f32_16x16x32_bf16(A1l, Bh[1][g], acc, 0, 0, 0);
                acc = __builtin_amdgcn_mfma_f32_16x16x32_bf16(A1h, Bl[1][g], acc, 0, 0, 0);
                acc = __builtin_amdgcn_mfma_f32_16x16x32_bf16(A2h, Bh[2][g], acc, 0, 0, 0);
                acc = __builtin_amdgcn_mfma_f32_16x16x32_bf16(A2l, Bh[2][g], acc, 0, 0, 0);
                acc = __builtin_amdgcn_mfma_f32_16x16x32_bf16(A2h, Bl[2][g], acc, 0, 0, 0);
                z[g] = acc;
            }
            const int nbase = ((buf ^ 1) * 2 + d) * 16;
            #pragma unroll
            for (int i = 0; i < 4; ++i) {
                float zi = z[0][i], zf = z[1][i], zg = z[2][i], zo = z[3][i];
                float cc = sigm(zf) * c4[i] + sigm(zi) * tanhfast(zg);
                float hh = sigm(zo) * tanhfast(cc);
                c4[i] = cc;
                int smp = (q << 2) + i;
                unsigned short bfh = f2bf(hh);
                unsigned short bfe = f2bf(hh - bf2f(bfh));
                unsigned int wself = ((unsigned)bfh << 16) | (unsigned)bfe;
                unsigned int wnbr = __shfl_xor(wself, 1);
                unsigned int outw = (r & 1) ? ((wself << 16) | (wnbr & 0xFFFFu))
                                            : ((wnbr & 0xFFFF0000u) | (wself >> 16));
                hpackU[(nbase + smp) * 68 + wofs] = outw;
                if constexpr (mode == 2) aacc[i] += pT[ts * 16 + smp] * hh;
                if constexpr (mode == 0) {
                    if (t == TT - 1) {
                        hfinL[smp * 128 + (d << 6) + u] = hh;
                        cfinL[smp * 128 + (d << 6) + u] = cc;
                    }
                }
            }
            __syncthreads();
        }
        if constexpr (mode == 1) {
            if (w == 0) {
                short8 A0h = *(const short8*)(hrd0);
                short8 A1h = *(const short8*)(hrd0 + 16);
                f32x4 sa = {0.f, 0.f, 0.f, 0.f};
                sa = __builtin_amdgcn_mfma_f32_16x16x32_bf16(A0h, Bq0h, sa, 0, 0, 0);
                sa = __builtin_amdgcn_mfma_f32_16x16x32_bf16(A1h, Bq1h, sa, 0, 0, 0);
                if (q == (r >> 2)) {
                    int tp = d ? 0 : (TT - 1);
                    sgridF[(d * 16 + r) * 128 + tp] = sa[r & 3];
                }
            }
            __syncthreads();
        }
        if constexpr (mode == 2) {
            #pragma unroll
            for (int i = 0; i < 4; ++i) {
                int smp = (q << 2) + i;
                attS[smp * 128 + (d << 6) + u] = aacc[i] / lS[smp];
            }
            __syncthreads();
        }
    };

    run_phase(IC<0>{});
    for (int o = tid; o < 2048; o += 512) {
        int kind = o >> 10, smp = (o >> 6) & 15, uu = o & 63;
        const float* src = kind ? (cfinL + smp * 128) : (hfinL + smp * 128);
        const float* Wm = kind ? Wsc : Wsh;
        float a = kind ? bsc[uu] : bsh[uu];
        #pragma unroll 4
        for (int j = 0; j < 128; ++j) a += src[j] * Wm[j * 64 + uu];
        (kind ? scS : shS)[smp * 64 + uu] = a;
    }
    __syncthreads();
    for (int o = tid; o < 2048; o += 512) {
        int smp = o >> 7, dd = o & 127;
        float a = bq[dd];
        #pragma unroll 4
        for (int j = 0; j < 64; ++j) a += shS[smp * 64 + j] * Wq[j * 128 + dd];
        qS[smp * 128 + dd] = a;
    }
    __syncthreads();
    if (w == 0) {
        #pragma unroll
        for (int j = 0; j < 8; ++j) {
            Bq0h[j] = (short)f2bf(qS[r * 128 + (d << 6) + q * 8 + j]);
            Bq1h[j] = (short)f2bf(qS[r * 128 + (d << 6) + 32 + q * 8 + j]);
        }
    }
    __syncthreads();

    run_phase(IC<1>{});
    {
        int smp = tid >> 5, sl = tid & 31;
        float sv[4];
        #pragma unroll
        for (int p = 0; p < 4; ++p) {
            int t = sl + 32 * p;
            sv[p] = sgridF[smp * 128 + t] + sgridF[(16 + smp) * 128 + t];
        }
        float m = fmaxf(fmaxf(sv[0], sv[1]), fmaxf(sv[2], sv[3]));
        #pragma unroll
        for (int mk = 1; mk < 32; mk <<= 1) m = fmaxf(m, __shfl_xor(m, mk));
        float lsum = 0.f;
        #pragma unroll
        for (int p = 0; p < 4; ++p) lsum += __expf(sv[p] - m);
        #pragma unroll
        for (int mk = 1; mk < 32; mk <<= 1) lsum += __shfl_xor(lsum, mk);
        __syncthreads();
        #pragma unroll
        for (int p = 0; p < 4; ++p) pT[(sl + 32 * p) * 16 + smp] = __expf(sv[p] - m);
        if (sl == 0) lS[smp] = lsum;
    }
    __syncthreads();

    run_phase(IC<2>{});

    for (int o = tid; o < 4096; o += 512) {
        int smp = o >> 8, col = o & 255;
        float a = db[col];
        #pragma unroll 4
        for (int j = 0; j < 128; ++j) a += attS[smp * 128 + j] * dk[j * 256 + col];
        #pragma unroll 4
        for (int j = 0; j < 64; ++j)  a += shS[smp * 64 + j] * dr[j * 256 + col];
        zdS[smp * 256 + col] = a;
    }
    __syncthreads();
    for (int o = tid; o < 1024; o += 512) {
        int smp = o >> 6, uu = o & 63;
        float zi = zdS[smp * 256 + uu], zf = zdS[smp * 256 + 64 + uu];
        float zg = zdS[smp * 256 + 128 + uu], zo = zdS[smp * 256 + 192 + uu];
        float cc = sigm(zf) * scS[smp * 64 + uu] + sigm(zi) * tanhfast(zg);
        hdS[smp * 64 + uu] = sigm(zo) * tanhfast(cc);
    }
    __syncthreads();
    {
        int smp = tid >> 5, v = tid & 31;
        float a = bo[v];
        #pragma unroll 4
        for (int j = 0; j < 64; ++j) a += hdS[smp * 64 + j] * Wo[j * 32 + v];
        float m = a;
        #pragma unroll
        for (int mk = 1; mk < 32; mk <<= 1) m = fmaxf(m, __shfl_xor(m, mk));
        float e = __expf(a - m);
        float s2 = e;
        #pragma unroll
        for (int mk = 1; mk < 32; mk <<= 1) s2 += __shfl_xor(s2, mk);
        out[(size_t)(sbase + smp) * VV + v] = e / s2;
    }
}

extern "C" void kernel_launch(void* const* d_in, const int* in_sizes, int n_in,
                              void* d_out, int out_size, void* d_ws, size_t ws_size,
                              hipStream_t stream) {
    const float* X   = (const float*)d_in[0];
    const int*   Yp  = (const int*)d_in[1];
    const float* lng = (const float*)d_in[2];
    const float* lnb = (const float*)d_in[3];
    const float* W1  = (const float*)d_in[4];
    const float* b1  = (const float*)d_in[5];
    const float* bng = (const float*)d_in[6];
    const float* bnb = (const float*)d_in[7];
    const float* bnm = (const float*)d_in[8];
    const float* bnv = (const float*)d_in[9];
    const float* W2  = (const float*)d_in[10];
    const float* b2  = (const float*)d_in[11];
    const float* W3  = (const float*)d_in[12];
    const float* b3  = (const float*)d_in[13];
    const float* fk  = (const float*)d_in[14];
    const float* fr  = (const float*)d_in[15];
    const float* fb  = (const float*)d_in[16];
    const float* bk  = (const float*)d_in[17];
    const float* br  = (const float*)d_in[18];
    const float* bbv = (const float*)d_in[19];
    const float* Wsh = (const float*)d_in[20];
    const float* bsh = (const float*)d_in[21];
    const float* Wsc = (const float*)d_in[22];
    const float* bsc = (const float*)d_in[23];
    const float* Wq  = (const float*)d_in[24];
    const float* bq  = (const float*)d_in[25];
    const float* dk  = (const float*)d_in[26];
    const float* dr  = (const float*)d_in[27];
    const float* db  = (const float*)d_in[28];
    const float* Wo  = (const float*)d_in[29];
    const float* bo  = (const float*)d_in[30];

    // ws layout: sqpk u32[B*T*8] | yv u16[B*T] | hfin f32[B*128] | cfin f32[B*128] | enc u16[cs*T*128]
    unsigned int*   sqpk = (unsigned int*)d_ws;
    unsigned short* yv   = (unsigned short*)(sqpk + (size_t)BB * TT * 8);
    float*          hfin = (float*)(yv + (size_t)BB * TT);
    float*          cfin = hfin + (size_t)BB * 128;
    unsigned int*   encp = (unsigned int*)(cfin + (size_t)BB * 128);
    const size_t baseB = (size_t)((char*)encp - (char*)d_ws);

    int nch = 0;
    if (ws_size >= baseB + (size_t)BB * TT * 128 * 2)            nch = 1;
    else if (ws_size >= baseB + (size_t)(BB / 2) * TT * 128 * 2) nch = 2;

    k_mlp2<<<768, 256, 0, stream>>>(X, Yp, lng, lnb, W1, b1, bng, bnb, bnm, bnv,
                                    W2, b2, W3, b3, sqpk, yv);
    if (nch) {
        const int cs = BB / nch;
        for (int c = 0; c < nch; ++c) {
            int s0 = c * cs;
            k_rnn1<<<cs / 16, 512, 0, stream>>>(sqpk, yv, fk, fr, fb, bk, br, bbv,
                                                encp, hfin, cfin, s0);
            k_att<<<cs, 256, 0, stream>>>((const unsigned short*)encp, hfin, cfin,
                                          Wsh, bsh, Wsc, bsc, Wq, bq,
                                          dk, dr, db, Wo, bo, (float*)d_out, s0);
        }
    } else {
        k_rnn<<<BB / 16, 512, 0, stream>>>(sqpk, yv, fk, fr, fb, bk, br, bbv,
                                           Wsh, bsh, Wsc, bsc, Wq, bq, dk, dr, db, Wo, bo,
                                           (float*)d_out);
    }
}